// Round 12
// baseline (4502.317 us; speedup 1.0000x reference)
//
#include <hip/hip_runtime.h>
#include <cstdint>
#include <cstddef>

#define DI __device__ __forceinline__

typedef __attribute__((ext_vector_type(8))) short short8;   // 8 bf16 = 4 VGPR (MFMA A/B frag)
typedef __attribute__((ext_vector_type(4))) float f32x4;    // MFMA C/D frag
typedef unsigned short u16;

DI u16 f2bf(float f) {
  union { float f; unsigned u; } v; v.f = f;
  unsigned r = v.u + 0x7fffu + ((v.u >> 16) & 1u);  // RNE
  return (u16)(r >> 16);
}
DI float bf2f(u16 h) {
  union { unsigned u; float f; } v; v.u = ((unsigned)h) << 16;
  return v.f;
}

DI void gload_lds16(const void* g, void* l) {
  __builtin_amdgcn_global_load_lds(
      (const __attribute__((address_space(1))) void*)g,
      (__attribute__((address_space(3))) void*)l, 16, 0, 0);
}

DI void atomAddF(float* p, float v) {
  __hip_atomic_fetch_add(p, v, __ATOMIC_RELAXED, __HIP_MEMORY_SCOPE_AGENT);
}

// split 4 f32 -> packed hi (RNE) and lo (trunc of exact residual) bf16 pairs
DI void split4(float4 v, uint2& hi, uint2& lo) {
  unsigned u0 = __float_as_uint(v.x), u1 = __float_as_uint(v.y);
  unsigned u2 = __float_as_uint(v.z), u3 = __float_as_uint(v.w);
  unsigned r0 = (u0 + 0x7fffu + ((u0 >> 16) & 1u)) & 0xffff0000u;
  unsigned r1 = (u1 + 0x7fffu + ((u1 >> 16) & 1u)) & 0xffff0000u;
  unsigned r2 = (u2 + 0x7fffu + ((u2 >> 16) & 1u)) & 0xffff0000u;
  unsigned r3 = (u3 + 0x7fffu + ((u3 >> 16) & 1u)) & 0xffff0000u;
  unsigned l0 = __float_as_uint(v.x - __uint_as_float(r0));
  unsigned l1 = __float_as_uint(v.y - __uint_as_float(r1));
  unsigned l2 = __float_as_uint(v.z - __uint_as_float(r2));
  unsigned l3 = __float_as_uint(v.w - __uint_as_float(r3));
  hi.x = __builtin_amdgcn_perm(r1, r0, 0x07060302u);
  hi.y = __builtin_amdgcn_perm(r3, r2, 0x07060302u);
  lo.x = __builtin_amdgcn_perm(l1, l0, 0x07060302u);
  lo.y = __builtin_amdgcn_perm(l3, l2, 0x07060302u);
}

// ---------------------------------------------------------------------------
// Split-bf16 emulated-f32 GEMM:  C = alpha * A(M,K) * B(N,K)^T (+bias)(GELU)
// A: two bf16 planes (hi at ptr, lo at ptr+planeA).
// B: BF32 -> raw f32, reg-staged + split in-register; else bf16 plane(s).
// TERMS: 3 = ah*bh + ah*bl + al*bh (~f32 fidelity, pre-router path);
//        2 = ah*bh + al*bh (post-router); 1 = ah*bh (LM head).
// BK fixed at 32: 64-byte LDS row stride is the conflict-free case (the BK=64
// variant tripled SQ_LDS_BANK_CONFLICT — measured round 11).
// OUTMODE: 0 f32 store, 1 split-bf16 store, 3 f32 C += v (atomic if SK>1),
//          4 MoE scatter. GATHER: 1 A-row gather, 2 epilogue scatter.
// ---------------------------------------------------------------------------
template<int BM, int BN, int WGM, int WGN, int OUTMODE, bool GELU, int GATHER,
         bool BF32, int SPLITK, int TERMS>
__global__ __launch_bounds__(256)
void gemm_bt(const u16* __restrict__ A, int lda, long planeA, long offA_hi, long offA_lo,
             const void* __restrict__ Bv, int ldb, long planeB, long offB_hi, long offB_lo,
             void* __restrict__ Cv, int ldc, long planeC, long offC_hi, long offC_lo,
             int K, float alpha,
             const float* __restrict__ bias, long offBias,
             const float* __restrict__ wf,
             const int* __restrict__ glist,
             const int* __restrict__ gcnt,
             const int* __restrict__ gmap,
             const int* __restrict__ gaoff)
{
  constexpr int BK = 32;
  constexpr int WM = BM / WGM, WN = BN / WGN;
  constexpr int FM = WM / 16, FN = WN / 16;
  constexpr int A_INST = (BM * BK) / (256 * 8);
  constexpr int B_INST = (BN * BK) / (256 * 8);
  constexpr int BF_INST = (BN * BK) / (256 * 4);
  static_assert(A_INST * 2048 == BM * BK && B_INST * 2048 == BN * BK, "tile sizing");

  // column-panel-contiguous linear id, then bijective XCD chunking (m204)
  int bx = blockIdx.x, by = blockIdx.y;
  {
    const int gy = gridDim.y;
    const int nwg = gridDim.x * gy;
    const int id = bx * gy + by;
    const int q = nwg >> 3, r = nwg & 7;
    const int xcd = id & 7, pos = id >> 3;
    const int nid = ((xcd < r) ? xcd * (q + 1) : r * (q + 1) + (xcd - r) * q) + pos;
    bx = nid / gy; by = nid % gy;
  }

  int e = 0, sk = 0, zb = 0, zh = 0, cnte = 0, lsb = 0;
  if constexpr (GATHER != 0) {
    e = gmap[by];
    if (e < 0) return;
    cnte = gcnt[e];
    lsb = by * BM - gaoff[e];
    if constexpr (SPLITK > 1) sk = blockIdx.z;
  } else if constexpr (SPLITK > 1) {
    sk = blockIdx.z;
  } else {
    zb = blockIdx.z >> 4; zh = blockIdx.z & 15;
  }

  __shared__ __align__(16) u16 Ash[BM * BK];
  __shared__ __align__(16) u16 Asl[(TERMS >= 2) ? BM * BK : 8];
  __shared__ __align__(16) u16 Bsh[BN * BK];
  __shared__ __align__(16) u16 Bsl[(TERMS == 3) ? BN * BK : 8];

  const int tid = threadIdx.x;
  const int lane = tid & 63, wid = tid >> 6;

  const u16* Ab = A + (size_t)zb * offA_hi + (size_t)zh * offA_lo
                    + (GATHER == 1 ? 0 : (size_t)(by * BM) * lda);
  const u16* Bb = (const u16*)Bv + (size_t)zb * offB_hi + (size_t)zh * offB_lo
                    + (size_t)(bx * BN) * ldb;
  const float* Bfb = (const float*)Bv + (size_t)e * offB_hi
                    + (size_t)(bx * BN) * ldb;

  int grow[A_INST];
  if constexpr (GATHER == 1) {
#pragma unroll
    for (int j = 0; j < A_INST; ++j) {
      int ee = (j * 256 + tid) * 8;
      int sl = lsb + (ee >> 5);
      grow[j] = (sl < cnte) ? (glist[e * 2048 + sl] >> 1) : 0;
    }
  }

  const int wm0 = (wid / WGN) * WM;
  const int wn0 = (wid % WGN) * WN;
  const int fr = lane & 15;
  const int kb = (lane >> 4) * 8;

  f32x4 acc[FM][FN] = {};

  const int Ksp = K / SPLITK;
  const int kbeg = sk * Ksp, kend = kbeg + Ksp;
  for (int k0 = kbeg; k0 < kend; k0 += BK) {
    __syncthreads();
#pragma unroll
    for (int j = 0; j < A_INST; ++j) {
      int ee = (j * 256 + tid) * 8;
      size_t gs = (GATHER == 1 ? (size_t)grow[j] : (size_t)(ee >> 5)) * lda + k0 + (ee & 31);
      gload_lds16(Ab + gs, (char*)Ash + (size_t)ee * 2);
      if constexpr (TERMS >= 2)
        gload_lds16(Ab + planeA + gs, (char*)Asl + (size_t)ee * 2);
    }
    if constexpr (BF32) {
#pragma unroll
      for (int j = 0; j < BF_INST; ++j) {
        int ee = (j * 256 + tid) * 4;
        float4 v = *(const float4*)(Bfb + (size_t)(ee >> 5) * ldb + k0 + (ee & 31));
        uint2 hi, lo;
        split4(v, hi, lo);
        *(uint2*)&Bsh[ee] = hi;
        if constexpr (TERMS == 3) *(uint2*)&Bsl[ee] = lo;
      }
    } else {
#pragma unroll
      for (int j = 0; j < B_INST; ++j) {
        int ee = (j * 256 + tid) * 8;
        size_t gs = (size_t)(ee >> 5) * ldb + k0 + (ee & 31);
        gload_lds16(Bb + gs, (char*)Bsh + (size_t)ee * 2);
        if constexpr (TERMS == 3)
          gload_lds16(Bb + planeB + gs, (char*)Bsl + (size_t)ee * 2);
      }
    }
    __syncthreads();

    short8 ah[FM], al_[FM], bh[FN], bl[FN];
#pragma unroll
    for (int mi = 0; mi < FM; ++mi) {
      int off = (wm0 + mi * 16 + fr) * BK + kb;
      ah[mi] = *(const short8*)&Ash[off];
      if constexpr (TERMS >= 2) al_[mi] = *(const short8*)&Asl[off];
    }
#pragma unroll
    for (int ni = 0; ni < FN; ++ni) {
      int off = (wn0 + ni * 16 + fr) * BK + kb;
      bh[ni] = *(const short8*)&Bsh[off];
      if constexpr (TERMS == 3) bl[ni] = *(const short8*)&Bsl[off];
    }
#pragma unroll
    for (int mi = 0; mi < FM; ++mi)
#pragma unroll
      for (int ni = 0; ni < FN; ++ni) {
        acc[mi][ni] = __builtin_amdgcn_mfma_f32_16x16x32_bf16(ah[mi], bh[ni], acc[mi][ni], 0, 0, 0);
        if constexpr (TERMS == 3)
          acc[mi][ni] = __builtin_amdgcn_mfma_f32_16x16x32_bf16(ah[mi], bl[ni], acc[mi][ni], 0, 0, 0);
        if constexpr (TERMS >= 2)
          acc[mi][ni] = __builtin_amdgcn_mfma_f32_16x16x32_bf16(al_[mi], bh[ni], acc[mi][ni], 0, 0, 0);
      }
  }
  __syncthreads();

  const size_t offC = (size_t)zb * offC_hi + (size_t)zh * offC_lo;
  const int row0 = by * BM + wm0 + (lane >> 4) * 4;
  const int col0 = bx * BN + wn0 + fr;
  const float* biasp = bias ? bias + (size_t)e * offBias : nullptr;
  const bool addBias = biasp && (SPLITK == 1 || sk == 0);

#pragma unroll
  for (int mi = 0; mi < FM; ++mi) {
#pragma unroll
    for (int ni = 0; ni < FN; ++ni) {
      const int col = col0 + ni * 16;
      const float bv = addBias ? biasp[col] : 0.f;
#pragma unroll
      for (int r = 0; r < 4; ++r) {
        const int row = row0 + mi * 16 + r;
        float v = acc[mi][ni][r] * alpha + bv;
        if constexpr (GELU) v = 0.5f * v * (1.f + erff(v * 0.70710678118f));
        if constexpr (OUTMODE == 4) {
          int sl = row - gaoff[e];
          if (sl < cnte) {
            int lv = glist[e * 2048 + sl];
            int tok = lv >> 1, rank = lv & 1;
            float* p = (float*)Cv + (size_t)rank * planeC + (size_t)tok * ldc + col;
            float out = wf[tok * 2 + rank] * v;
            if constexpr (SPLITK > 1) atomAddF(p, out); else *p = out;
          }
        } else {
          const size_t idx = offC + (size_t)row * ldc + col;
          if constexpr (OUTMODE == 1) {
            u16 hh = f2bf(v);
            u16 ll = f2bf(v - bf2f(hh));
            ((u16*)Cv)[idx] = hh;
            ((u16*)Cv)[idx + planeC] = ll;
          } else if constexpr (OUTMODE == 3) {
            if constexpr (SPLITK > 1) atomAddF((float*)Cv + idx, v);
            else ((float*)Cv)[idx] += v;
          } else {
            ((float*)Cv)[idx] = v;
          }
        }
      }
    }
  }
}

// ---------------------------------------------------------------------------
// Fused attention: ctx = softmax(q k^T / 8) @ v, one block per (bh, 128-q-tile)
// (verified round-9 structure, unchanged)
// ---------------------------------------------------------------------------
__global__ __launch_bounds__(512)
void attn_fused(const u16* __restrict__ qkv, long planeQ,
                const u16* __restrict__ vT, long planeV,
                u16* __restrict__ ctxs, long planeC)
{
  constexpr int BK = 32, S = 512;
  extern __shared__ __align__(16) char smem[];
  u16* Ash = (u16*)smem;
  u16* Asl = Ash + 128 * 32;
  u16* Bsh = Asl + 128 * 32;
  u16* Bsl = Bsh + 512 * 32;
  float* redM = (float*)(Bsl + 512 * 32);
  float* redS = redM + 512;
  u16* Ph = (u16*)smem;
  u16* Pl = Ph + 128 * 32;
  u16* Vh = Pl + 128 * 32;
  u16* Vl = Vh + 64 * 32;

  const int tid = threadIdx.x, lane = tid & 63, wid = tid >> 6;
  const int bh = blockIdx.z, zb = bh >> 4, zh = bh & 15;
  const int qt = blockIdx.y;
  const u16* Ab = qkv + (size_t)zb * (512 * 3072) + (size_t)zh * 64
                      + (size_t)(qt * 128) * 3072;
  const u16* Bb = qkv + (size_t)zb * (512 * 3072) + (size_t)zh * 64 + 1024;
  const u16* vt = vT + (size_t)bh * (64 * 512);

  const int wr = wid >> 2, wc = wid & 3;
  const int fr = lane & 15, kb = (lane >> 4) * 8, g = lane >> 4;

  f32x4 acc[4][8] = {};

  for (int k0 = 0; k0 < 64; k0 += BK) {
    __syncthreads();
    {
      int ee = tid * 8;
      size_t gs = (size_t)(ee >> 5) * 3072 + k0 + (ee & 31);
      gload_lds16(Ab + gs,          (char*)Ash + (size_t)ee * 2);
      gload_lds16(Ab + planeQ + gs, (char*)Asl + (size_t)ee * 2);
    }
#pragma unroll
    for (int j = 0; j < 4; ++j) {
      int ee = (j * 512 + tid) * 8;
      size_t gs = (size_t)(ee >> 5) * 3072 + k0 + (ee & 31);
      gload_lds16(Bb + gs,          (char*)Bsh + (size_t)ee * 2);
      gload_lds16(Bb + planeQ + gs, (char*)Bsl + (size_t)ee * 2);
    }
    __syncthreads();

    short8 ah[4], al_[4];
#pragma unroll
    for (int mi = 0; mi < 4; ++mi) {
      int off = (wr * 64 + mi * 16 + fr) * BK + kb;
      ah[mi]  = *(const short8*)&Ash[off];
      al_[mi] = *(const short8*)&Asl[off];
    }
#pragma unroll
    for (int ni = 0; ni < 8; ++ni) {
      int off = (wc * 128 + ni * 16 + fr) * BK + kb;
      short8 bhv = *(const short8*)&Bsh[off];
      short8 blv = *(const short8*)&Bsl[off];
#pragma unroll
      for (int mi = 0; mi < 4; ++mi) {
        acc[mi][ni] = __builtin_amdgcn_mfma_f32_16x16x32_bf16(ah[mi],  bhv, acc[mi][ni], 0, 0, 0);
        acc[mi][ni] = __builtin_amdgcn_mfma_f32_16x16x32_bf16(ah[mi],  blv, acc[mi][ni], 0, 0, 0);
        acc[mi][ni] = __builtin_amdgcn_mfma_f32_16x16x32_bf16(al_[mi], bhv, acc[mi][ni], 0, 0, 0);
      }
    }
  }

#pragma unroll
  for (int mi = 0; mi < 4; ++mi)
#pragma unroll
    for (int ni = 0; ni < 8; ++ni)
#pragma unroll
      for (int r = 0; r < 4; ++r) acc[mi][ni][r] *= 0.125f;

  float m[4][4];
#pragma unroll
  for (int mi = 0; mi < 4; ++mi)
#pragma unroll
    for (int r = 0; r < 4; ++r) {
      float v = acc[mi][0][r];
#pragma unroll
      for (int ni = 1; ni < 8; ++ni) v = fmaxf(v, acc[mi][ni][r]);
      v = fmaxf(v, __shfl_xor(v, 1));
      v = fmaxf(v, __shfl_xor(v, 2));
      v = fmaxf(v, __shfl_xor(v, 4));
      v = fmaxf(v, __shfl_xor(v, 8));
      m[mi][r] = v;
    }
  if (fr == 0) {
#pragma unroll
    for (int mi = 0; mi < 4; ++mi)
#pragma unroll
      for (int r = 0; r < 4; ++r)
        redM[wr * 256 + (g * 4 + mi * 16 + r) * 4 + wc] = m[mi][r];
  }
  __syncthreads();
#pragma unroll
  for (int mi = 0; mi < 4; ++mi)
#pragma unroll
    for (int r = 0; r < 4; ++r) {
      const float* p = &redM[wr * 256 + (g * 4 + mi * 16 + r) * 4];
      m[mi][r] = fmaxf(fmaxf(p[0], p[1]), fmaxf(p[2], p[3]));
    }

  float ssum[4][4];
#pragma unroll
  for (int mi = 0; mi < 4; ++mi)
#pragma unroll
    for (int r = 0; r < 4; ++r) {
      float ss = 0.f;
#pragma unroll
      for (int ni = 0; ni < 8; ++ni) {
        float p = __expf(acc[mi][ni][r] - m[mi][r]);
        acc[mi][ni][r] = p;
        ss += p;
      }
      ss += __shfl_xor(ss, 1);
      ss += __shfl_xor(ss, 2);
      ss += __shfl_xor(ss, 4);
      ss += __shfl_xor(ss, 8);
      ssum[mi][r] = ss;
    }
  if (fr == 0) {
#pragma unroll
    for (int mi = 0; mi < 4; ++mi)
#pragma unroll
      for (int r = 0; r < 4; ++r)
        redS[wr * 256 + (g * 4 + mi * 16 + r) * 4 + wc] = ssum[mi][r];
  }
  __syncthreads();

#pragma unroll
  for (int mi = 0; mi < 4; ++mi)
#pragma unroll
    for (int r = 0; r < 4; ++r) {
      const float* p = &redS[wr * 256 + (g * 4 + mi * 16 + r) * 4];
      const float inv = 1.f / (p[0] + p[1] + p[2] + p[3]);
#pragma unroll
      for (int ni = 0; ni < 8; ++ni) acc[mi][ni][r] *= inv;
    }

  f32x4 c[4] = {};
#pragma unroll
  for (int ks = 0; ks < 16; ++ks) {
    const int k0 = ks * 32;
    __syncthreads();
    if (wc == (ks >> 2)) {
      const int ni0 = (ks & 3) * 2;
#pragma unroll
      for (int mi = 0; mi < 4; ++mi)
#pragma unroll
        for (int dni = 0; dni < 2; ++dni)
#pragma unroll
          for (int r = 0; r < 4; ++r) {
            float v = acc[mi][ni0 + dni][r];
            u16 h = f2bf(v);
            u16 lo = f2bf(v - bf2f(h));
            int row = wr * 64 + mi * 16 + g * 4 + r;
            int koff = dni * 16 + fr;
            Ph[row * 32 + koff] = h;
            Pl[row * 32 + koff] = lo;
          }
    }
    {
      int ee = (tid & 255) * 8;
      size_t gs = (size_t)(ee >> 5) * 512 + k0 + (ee & 31);
      if (tid < 256) gload_lds16(vt + gs,          (char*)Vh + (size_t)ee * 2);
      else           gload_lds16(vt + planeV + gs, (char*)Vl + (size_t)ee * 2);
    }
    __syncthreads();

    short8 pah = *(const short8*)&Ph[(wid * 16 + fr) * 32 + kb];
    short8 pal = *(const short8*)&Pl[(wid * 16 + fr) * 32 + kb];
#pragma unroll
    for (int ni = 0; ni < 4; ++ni) {
      short8 vbh = *(const short8*)&Vh[(ni * 16 + fr) * 32 + kb];
      short8 vbl = *(const short8*)&Vl[(ni * 16 + fr) * 32 + kb];
      c[ni] = __builtin_amdgcn_mfma_f32_16x16x32_bf16(pah, vbh, c[ni], 0, 0, 0);
      c[ni] = __builtin_amdgcn_mfma_f32_16x16x32_bf16(pah, vbl, c[ni], 0, 0, 0);
      c[ni] = __builtin_amdgcn_mfma_f32_16x16x32_bf16(pal, vbh, c[ni], 0, 0, 0);
    }
  }

#pragma unroll
  for (int ni = 0; ni < 4; ++ni)
#pragma unroll
    for (int r = 0; r < 4; ++r) {
      int row = qt * 128 + wid * 16 + g * 4 + r;
      int d = ni * 16 + fr;
      size_t idx = ((size_t)zb * 512 + row) * 1024 + zh * 64 + d;
      float v = c[ni][r];
      u16 h = f2bf(v);
      u16 lo = f2bf(v - bf2f(h));
      ctxs[idx] = h;
      ctxs[idx + planeC] = lo;
    }
}

// ---------------------------------------------------------------------------
__global__ __launch_bounds__(256)
void embed_kernel(const int* __restrict__ ids, const float* __restrict__ tok,
                  const float* __restrict__ pos, float* __restrict__ x,
                  u16* __restrict__ xs, long plane)
{
  const int t = blockIdx.x, c = threadIdx.x;
  const int id = ids[t], s = t & 511;
  float4 tv = ((const float4*)(tok + (size_t)id * 1024))[c];
  float4 pv = ((const float4*)(pos + (size_t)s * 1024))[c];
  float o[4] = {tv.x + pv.x, tv.y + pv.y, tv.z + pv.z, tv.w + pv.w};
  ((float4*)(x + (size_t)t * 1024))[c] = *(float4*)o;
  uint2 uh, ul;
  u16 h0 = f2bf(o[0]), h1 = f2bf(o[1]), h2 = f2bf(o[2]), h3 = f2bf(o[3]);
  uh.x = (unsigned)h0 | ((unsigned)h1 << 16);
  uh.y = (unsigned)h2 | ((unsigned)h3 << 16);
  ul.x = (unsigned)f2bf(o[0] - bf2f(h0)) | ((unsigned)f2bf(o[1] - bf2f(h1)) << 16);
  ul.y = (unsigned)f2bf(o[2] - bf2f(h2)) | ((unsigned)f2bf(o[3] - bf2f(h3)) << 16);
  const size_t idx = (size_t)t * 1024 + c * 4;
  *(uint2*)(xs + idx) = uh;
  *(uint2*)(xs + plane + idx) = ul;
}

// ---------------------------------------------------------------------------
__global__ __launch_bounds__(256)
void ln_kernel(float* __restrict__ x, const float* __restrict__ g,
               const float* __restrict__ b, u16* __restrict__ xs, long plane)
{
  const int row = blockIdx.x, t = threadIdx.x;
  float4 xv = ((const float4*)(x + (size_t)row * 1024))[t];
  float s = xv.x + xv.y + xv.z + xv.w;
  float q = xv.x * xv.x + xv.y * xv.y + xv.z * xv.z + xv.w * xv.w;
#pragma unroll
  for (int o = 32; o; o >>= 1) { s += __shfl_xor(s, o); q += __shfl_xor(q, o); }
  __shared__ float ss[4], qq[4];
  const int wid = t >> 6;
  if ((t & 63) == 0) { ss[wid] = s; qq[wid] = q; }
  __syncthreads();
  s = ss[0] + ss[1] + ss[2] + ss[3];
  q = qq[0] + qq[1] + qq[2] + qq[3];
  const float mean = s * (1.f / 1024.f);
  const float var = q * (1.f / 1024.f) - mean * mean;
  const float rstd = 1.f / sqrtf(var + 1e-5f);
  float4 gv = ((const float4*)g)[t];
  float4 bv = ((const float4*)b)[t];
  float o[4];
  o[0] = (xv.x - mean) * rstd * gv.x + bv.x;
  o[1] = (xv.y - mean) * rstd * gv.y + bv.y;
  o[2] = (xv.z - mean) * rstd * gv.z + bv.z;
  o[3] = (xv.w - mean) * rstd * gv.w + bv.w;
  ((float4*)(x + (size_t)row * 1024))[t] = *(float4*)o;
  uint2 uh, ul;
  u16 h0 = f2bf(o[0]), h1 = f2bf(o[1]), h2 = f2bf(o[2]), h3 = f2bf(o[3]);
  uh.x = (unsigned)h0 | ((unsigned)h1 << 16);
  uh.y = (unsigned)h2 | ((unsigned)h3 << 16);
  ul.x = (unsigned)f2bf(o[0] - bf2f(h0)) | ((unsigned)f2bf(o[1] - bf2f(h1)) << 16);
  ul.y = (unsigned)f2bf(o[2] - bf2f(h2)) | ((unsigned)f2bf(o[3] - bf2f(h3)) << 16);
  const size_t idx = (size_t)row * 1024 + t * 4;
  *(uint2*)(xs + idx) = uh;
  *(uint2*)(xs + plane + idx) = ul;
}

// ---------------------------------------------------------------------------
// V transpose on both planes: vT[bh][d][s] = qkv[b*512+s][2048+h*64+d]
// ---------------------------------------------------------------------------
__global__ __launch_bounds__(256)
void vtrans_kernel(const u16* __restrict__ qkv, u16* __restrict__ vT,
                   long planeQ, long planeV)
{
  __shared__ u16 tile[64][68];
  const u16* src = qkv + (size_t)blockIdx.z * planeQ;
  u16* dst = vT + (size_t)blockIdx.z * planeV;
  const int s0 = blockIdx.x << 6;
  const int bh = blockIdx.y, b = bh >> 4, h = bh & 15;
  const int t = threadIdx.x;
#pragma unroll
  for (int j = 0; j < 16; ++j) {
    int idx = j * 256 + t;
    int sl = idx >> 6, d = idx & 63;
    tile[sl][d] = src[(size_t)(b * 512 + s0 + sl) * 3072 + 2048 + h * 64 + d];
  }
  __syncthreads();
#pragma unroll
  for (int j = 0; j < 16; ++j) {
    int idx = j * 256 + t;
    int d = idx >> 6, sl = idx & 63;
    dst[(size_t)bh * (64 * 512) + (size_t)d * 512 + s0 + sl] = tile[sl][d];
  }
}

// ---------------------------------------------------------------------------
__global__ __launch_bounds__(256)
void router_kernel(const float* __restrict__ x, const float* __restrict__ Wr,
                   const float* __restrict__ br, int2* __restrict__ er,
                   float2* __restrict__ wf)
{
  const int lane = threadIdx.x & 63, wid = threadIdx.x >> 6;
  const int t = blockIdx.x * 4 + wid;
  const float* xr = x + (size_t)t * 1024;
  float xv[16];
#pragma unroll
  for (int j = 0; j < 16; ++j) xv[j] = xr[j * 64 + lane];
  float p[8];
#pragma unroll
  for (int e = 0; e < 8; ++e) {
    const float* wr = Wr + (size_t)e * 1024;
    float s = 0.f;
#pragma unroll
    for (int j = 0; j < 16; ++j) s += xv[j] * wr[j * 64 + lane];
#pragma unroll
    for (int o = 32; o; o >>= 1) s += __shfl_xor(s, o);
    p[e] = s + br[e];
  }
  float m = p[0];
#pragma unroll
  for (int e = 1; e < 8; ++e) m = fmaxf(m, p[e]);
#pragma unroll
  for (int e = 0; e < 8; ++e) p[e] = __expf(p[e] - m);
  int i1 = -1; float v1 = -1.f;
#pragma unroll
  for (int e = 0; e < 8; ++e) if (p[e] > v1) { v1 = p[e]; i1 = e; }
  int i2 = -1; float v2 = -1.f;
#pragma unroll
  for (int e = 0; e < 8; ++e) if (e != i1 && p[e] > v2) { v2 = p[e]; i2 = e; }
  const float inv = 1.f / (v1 + v2);
  if (lane == 0) {
    er[t] = make_int2(i1, i2);
    wf[t] = make_float2(v1 * inv, v2 * inv);
  }
}

// ---------------------------------------------------------------------------
__global__ __launch_bounds__(256)
void build_lists(const int2* __restrict__ er, int* __restrict__ cnt,
                 int* __restrict__ list)
{
  const int t = blockIdx.x * 256 + threadIdx.x;
  int2 e = er[t];
  int s0 = atomicAdd(&cnt[e.x], 1); list[e.x * 2048 + s0] = t * 2;
  int s1 = atomicAdd(&cnt[e.y], 1); list[e.y * 2048 + s1] = t * 2 + 1;
}

// ---------------------------------------------------------------------------
__global__ void finalize_lists(const int* __restrict__ cnt, int* __restrict__ aoff,
                               int* __restrict__ block2e, int nb)
{
  if (threadIdx.x != 0 || blockIdx.x != 0) return;
  for (int b = 0; b < nb; ++b) block2e[b] = -1;
  int off = 0;
  for (int e = 0; e < 8; ++e) {
    aoff[e] = off;
    int pe = ((cnt[e] + 127) >> 7) << 7;
    for (int b = off >> 7; b < (off + pe) >> 7; ++b) block2e[b] = e;
    off += pe;
  }
  aoff[8] = off;
}

// ---------------------------------------------------------------------------
__global__ __launch_bounds__(256)
void combine_split(const float* __restrict__ o0, const float* __restrict__ o1,
                   u16* __restrict__ dh, long plane)
{
  const long i = ((long)blockIdx.x * 256 + threadIdx.x) * 8;
  float4 a0 = ((const float4*)o0)[i / 4];
  float4 a1 = ((const float4*)o0)[i / 4 + 1];
  float4 b0 = ((const float4*)o1)[i / 4];
  float4 b1 = ((const float4*)o1)[i / 4 + 1];
  float v[8] = {a0.x + b0.x, a0.y + b0.y, a0.z + b0.z, a0.w + b0.w,
                a1.x + b1.x, a1.y + b1.y, a1.z + b1.z, a1.w + b1.w};
  u16 h[8], l[8];
#pragma unroll
  for (int j = 0; j < 8; ++j) {
    h[j] = f2bf(v[j]);
    l[j] = f2bf(v[j] - bf2f(h[j]));
  }
  uint4 uh, ul;
  uh.x = (unsigned)h[0] | ((unsigned)h[1] << 16); ul.x = (unsigned)l[0] | ((unsigned)l[1] << 16);
  uh.y = (unsigned)h[2] | ((unsigned)h[3] << 16); ul.y = (unsigned)l[2] | ((unsigned)l[3] << 16);
  uh.z = (unsigned)h[4] | ((unsigned)h[5] << 16); ul.z = (unsigned)l[4] | ((unsigned)l[5] << 16);
  uh.w = (unsigned)h[6] | ((unsigned)h[7] << 16); ul.w = (unsigned)l[6] | ((unsigned)l[7] << 16);
  ((uint4*)dh)[i / 8] = uh;
  ((uint4*)(dh + plane))[i / 8] = ul;
}

// ---------------------------------------------------------------------------
__global__ __launch_bounds__(256)
void trunc_bf16(const float* __restrict__ s, u16* __restrict__ d)
{
  const long i = ((long)blockIdx.x * 256 + threadIdx.x) * 8;
  float4 a = ((const float4*)s)[i / 4];
  float4 b = ((const float4*)s)[i / 4 + 1];
  uint4 u;
  u.x = (unsigned)f2bf(a.x) | ((unsigned)f2bf(a.y) << 16);
  u.y = (unsigned)f2bf(a.z) | ((unsigned)f2bf(a.w) << 16);
  u.z = (unsigned)f2bf(b.x) | ((unsigned)f2bf(b.y) << 16);
  u.w = (unsigned)f2bf(b.z) | ((unsigned)f2bf(b.w) << 16);
  ((uint4*)d)[i / 8] = u;
}

// ---------------------------------------------------------------------------

extern "C" void kernel_launch(void* const* d_in, const int* in_sizes, int n_in,
                              void* d_out, int out_size, void* d_ws, size_t ws_size,
                              hipStream_t stream)
{
  (void)in_sizes; (void)n_in; (void)out_size;
  const int*   ids  = (const int*)d_in[0];
  const float* tok  = (const float*)d_in[2];
  const float* pos  = (const float*)d_in[3];
  const float* Wqkv = (const float*)d_in[4];
  const float* bqkv = (const float*)d_in[5];
  const float* Wo   = (const float*)d_in[6];
  const float* bo   = (const float*)d_in[7];
  const float* ln1g = (const float*)d_in[8];
  const float* ln1b = (const float*)d_in[9];
  const float* ln2g = (const float*)d_in[10];
  const float* ln2b = (const float*)d_in[11];
  const float* W1   = (const float*)d_in[12];
  const float* b1   = (const float*)d_in[13];
  const float* W2   = (const float*)d_in[14];
  const float* b2   = (const float*)d_in[15];
  const float* Wr   = (const float*)d_in[16];
  const float* br   = (const float*)d_in[17];
  const float* We1  = (const float*)d_in[18];
  const float* be1  = (const float*)d_in[19];
  const float* We2  = (const float*)d_in[20];
  const float* be2  = (const float*)d_in[21];
  const float* Wout = (const float*)d_in[22];
  const float* bout = (const float*)d_in[23];

  constexpr int T = 2048, D = 1024, S = 512, Bb = 4, H = 16, dh = 64, F = 4096,
                L = 12, E = 8, V = 32000;
  constexpr int NB = (2 * T + E * 127) / 128 + 1;   // padded slot blocks (40)

  constexpr long PX  = (long)T * D;
  constexpr long PQ  = (long)T * 3 * D;
  constexpr long PFE = (long)(NB * 128) * F;        // padded expert hidden
  constexpr long PV  = (long)Bb * H * dh * S;

  char* w = (char*)d_ws;
  size_t o = 0;
  auto alloc = [&](size_t bytes) -> void* {
    void* p = w + o; o = (o + bytes + 255) & ~(size_t)255; return p;
  };
  float* x    = (float*)alloc((size_t)T * D * 4);
  u16* xs   = (u16*)alloc((size_t)2 * PX * 2);
  u16* moes = (u16*)alloc((size_t)2 * PX * 2);
  u16* qkvs = (u16*)alloc((size_t)2 * PQ * 2);
  u16* ctxs = (u16*)alloc((size_t)2 * PX * 2);
  u16* ffs  = (u16*)alloc((size_t)2 * PFE * 2);
  u16* vTs  = (u16*)alloc((size_t)2 * PV * 2);
  u16* woutb = (u16*)alloc((size_t)V * D * 2);
  float* outr = (float*)alloc((size_t)2 * PX * 4);
  int2*   er  = (int2*)alloc((size_t)T * 8);
  float2* wf  = (float2*)alloc((size_t)T * 8);
  int*    cnt = (int*)alloc((size_t)E * 4);
  int*    list= (int*)alloc((size_t)E * T * 4);
  int*    aoff= (int*)alloc((size_t)(E + 1) * 4);
  int*    b2e = (int*)alloc((size_t)NB * 4);
  if (o > ws_size) return;  // output stays poisoned -> visible failure

  embed_kernel<<<T, 256, 0, stream>>>(ids, tok, pos, x, xs, PX);
  trunc_bf16<<<(V * D) / 2048, 256, 0, stream>>>(Wout, woutb);

  constexpr size_t ATTN_LDS = (4096 + 4096 + 16384 + 16384) * 2 + 2 * 512 * 4;

  for (int l = 0; l < L; ++l) {
    // qkv = xs @ Wqkv^T + bqkv -> split qkvs
    gemm_bt<128,128,2,2,1,false,0,true,1,3>
        <<<dim3(3 * D / 128, T / 128, 1), 256, 0, stream>>>(
        xs, D, PX, 0, 0, Wqkv + (size_t)l * 3 * D * D, D, 0, 0, 0,
        qkvs, 3 * D, PQ, 0, 0, D, 1.f, bqkv + (size_t)l * 3 * D, 0,
        nullptr, nullptr, nullptr, nullptr, nullptr);
    vtrans_kernel<<<dim3(S / 64, Bb * H, 2), 256, 0, stream>>>(qkvs, vTs, PQ, PV);
    // ctx = softmax(q k^T / 8) @ v  (fused)
    attn_fused<<<dim3(1, S / 128, Bb * H), 512, ATTN_LDS, stream>>>(
        qkvs, PQ, vTs, PV, ctxs, PX);
    // x += ctx @ Wo^T + bo   (split-K=2, atomic f32)
    gemm_bt<128,128,2,2,3,false,0,true,2,3>
        <<<dim3(D / 128, T / 128, 2), 256, 0, stream>>>(
        ctxs, D, PX, 0, 0, Wo + (size_t)l * D * D, D, 0, 0, 0,
        x, D, 0, 0, 0, D, 1.f, bo + (size_t)l * D, 0,
        nullptr, nullptr, nullptr, nullptr, nullptr);
    ln_kernel<<<T, 256, 0, stream>>>(x, ln1g + (size_t)l * D, ln1b + (size_t)l * D, xs, PX);
    // ff = gelu(xs @ W1^T + b1) -> split ffs
    gemm_bt<128,128,2,2,1,true,0,true,1,3>
        <<<dim3(F / 128, T / 128, 1), 256, 0, stream>>>(
        xs, D, PX, 0, 0, W1 + (size_t)l * F * D, D, 0, 0, 0,
        ffs, F, (long)T * F, 0, 0, D, 1.f, b1 + (size_t)l * F, 0,
        nullptr, nullptr, nullptr, nullptr, nullptr);
    // x += ffs @ W2^T + b2   (split-K=4, atomic f32)
    gemm_bt<128,128,2,2,3,false,0,true,4,3>
        <<<dim3(D / 128, T / 128, 4), 256, 0, stream>>>(
        ffs, F, (long)T * F, 0, 0, W2 + (size_t)l * D * F, F, 0, 0, 0,
        x, D, 0, 0, 0, F, 1.f, b2 + (size_t)l * D, 0,
        nullptr, nullptr, nullptr, nullptr, nullptr);
    ln_kernel<<<T, 256, 0, stream>>>(x, ln2g + (size_t)l * D, ln2b + (size_t)l * D, xs, PX);
  }

  // ---- sparse top-2 MoE (batched experts via 128-padded slot blocks) ----
  router_kernel<<<T / 4, 256, 0, stream>>>(x, Wr, br, er, wf);
  hipMemsetAsync(cnt, 0, E * 4, stream);
  build_lists<<<T / 256, 256, 0, stream>>>(er, cnt, list);
  finalize_lists<<<1, 64, 0, stream>>>(cnt, aoff, b2e, NB);
  hipMemsetAsync(outr, 0, (size_t)2 * PX * 4, stream);

  gemm_bt<128,128,2,2,1,true,1,true,1,2>
      <<<dim3(F / 128, NB, 1), 256, 0, stream>>>(
      xs, D, PX, 0, 0, We1, D, 0, (long)F * D, 0,
      ffs, F, PFE, 0, 0, D, 1.f, be1, F,
      nullptr, list, cnt, b2e, aoff);
  gemm_bt<128,128,2,2,4,false,2,true,2,2>
      <<<dim3(D / 128, NB, 2), 256, 0, stream>>>(
      ffs, F, PFE, 0, 0, We2, F, 0, (long)D * F, 0,
      outr, D, PX, 0, 0, F, 1.f, be2, D,
      (const float*)wf, list, cnt, b2e, aoff);

  combine_split<<<(PX / 2048), 256, 0, stream>>>(outr, outr + PX, moes, PX);

  // logits = moes(hi) @ Wout(bf16)^T + bout -> f32 d_out
  // 1-term, 128x256 tile: 32 MFMA per barrier-pair at the conflict-free
  // 64B LDS row stride (BK=32).
  gemm_bt<128,256,2,2,0,false,0,false,1,1>
      <<<dim3(V / 256, T / 128, 1), 256, 0, stream>>>(
      moes, D, PX, 0, 0, woutb, D, 0, 0, 0,
      (float*)d_out, V, 0, 0, 0,
      D, 1.f, bout, 0, nullptr, nullptr, nullptr, nullptr, nullptr);
}

// Round 13
// 4336.179 us; speedup vs baseline: 1.0383x; 1.0383x over previous
//
#include <hip/hip_runtime.h>
#include <cstdint>
#include <cstddef>

#define DI __device__ __forceinline__

typedef __attribute__((ext_vector_type(8))) short short8;   // 8 bf16 = 4 VGPR (MFMA A/B frag)
typedef __attribute__((ext_vector_type(4))) float f32x4;    // MFMA C/D frag
typedef unsigned short u16;

DI u16 f2bf(float f) {
  union { float f; unsigned u; } v; v.f = f;
  unsigned r = v.u + 0x7fffu + ((v.u >> 16) & 1u);  // RNE
  return (u16)(r >> 16);
}
DI float bf2f(u16 h) {
  union { unsigned u; float f; } v; v.u = ((unsigned)h) << 16;
  return v.f;
}

DI void gload_lds16(const void* g, void* l) {
  __builtin_amdgcn_global_load_lds(
      (const __attribute__((address_space(1))) void*)g,
      (__attribute__((address_space(3))) void*)l, 16, 0, 0);
}

DI void atomAddF(float* p, float v) {
  __hip_atomic_fetch_add(p, v, __ATOMIC_RELAXED, __HIP_MEMORY_SCOPE_AGENT);
}

// split 4 f32 -> packed hi (RNE) and lo (trunc of exact residual) bf16 pairs
DI void split4(float4 v, uint2& hi, uint2& lo) {
  unsigned u0 = __float_as_uint(v.x), u1 = __float_as_uint(v.y);
  unsigned u2 = __float_as_uint(v.z), u3 = __float_as_uint(v.w);
  unsigned r0 = (u0 + 0x7fffu + ((u0 >> 16) & 1u)) & 0xffff0000u;
  unsigned r1 = (u1 + 0x7fffu + ((u1 >> 16) & 1u)) & 0xffff0000u;
  unsigned r2 = (u2 + 0x7fffu + ((u2 >> 16) & 1u)) & 0xffff0000u;
  unsigned r3 = (u3 + 0x7fffu + ((u3 >> 16) & 1u)) & 0xffff0000u;
  unsigned l0 = __float_as_uint(v.x - __uint_as_float(r0));
  unsigned l1 = __float_as_uint(v.y - __uint_as_float(r1));
  unsigned l2 = __float_as_uint(v.z - __uint_as_float(r2));
  unsigned l3 = __float_as_uint(v.w - __uint_as_float(r3));
  hi.x = __builtin_amdgcn_perm(r1, r0, 0x07060302u);
  hi.y = __builtin_amdgcn_perm(r3, r2, 0x07060302u);
  lo.x = __builtin_amdgcn_perm(l1, l0, 0x07060302u);
  lo.y = __builtin_amdgcn_perm(l3, l2, 0x07060302u);
}

// ---------------------------------------------------------------------------
// Split-bf16 emulated-f32 GEMM:  C = alpha * A(M,K) * B(N,K)^T (+bias)(GELU)
// A: two bf16 planes (hi at ptr, lo at ptr+planeA).
// B: BF32 -> raw f32, reg-staged + split in-register; else bf16 plane(s).
// TERMS: 3 = ah*bh + ah*bl + al*bh (~f32 fidelity, pre-router path);
//        2 = ah*bh + al*bh (post-router); 1 = ah*bh (LM head).
// NSUB: K-sub-tiles per barrier pair, each its own 8 KB LDS sub-buffer at
//   the conflict-free 64B row stride. NSUB=2 doubles MFMA per barrier
//   WITHOUT the BK=64 bank-conflict (r11: 3x conflicts) or the BN=256
//   VGPR/occupancy cliff (r12: 11% occ).
// OUTMODE: 0 f32 store, 1 split-bf16 store, 3 f32 C += v (atomic if SK>1),
//          4 MoE scatter. GATHER: 1 A-row gather, 2 epilogue scatter.
// ---------------------------------------------------------------------------
template<int BM, int BN, int WGM, int WGN, int OUTMODE, bool GELU, int GATHER,
         bool BF32, int SPLITK, int TERMS, int NSUB = 1>
__global__ __launch_bounds__(256)
void gemm_bt(const u16* __restrict__ A, int lda, long planeA, long offA_hi, long offA_lo,
             const void* __restrict__ Bv, int ldb, long planeB, long offB_hi, long offB_lo,
             void* __restrict__ Cv, int ldc, long planeC, long offC_hi, long offC_lo,
             int K, float alpha,
             const float* __restrict__ bias, long offBias,
             const float* __restrict__ wf,
             const int* __restrict__ glist,
             const int* __restrict__ gcnt,
             const int* __restrict__ gmap,
             const int* __restrict__ gaoff)
{
  constexpr int BK = 32;                 // per-sub-buffer K (64B stride)
  constexpr int KSTEP = BK * NSUB;
  constexpr int WM = BM / WGM, WN = BN / WGN;
  constexpr int FM = WM / 16, FN = WN / 16;
  constexpr int A_INST = (BM * BK) / (256 * 8);
  constexpr int B_INST = (BN * BK) / (256 * 8);
  constexpr int BF_INST = (BN * BK) / (256 * 4);
  static_assert(A_INST * 2048 == BM * BK && B_INST * 2048 == BN * BK, "tile sizing");

  // column-panel-contiguous linear id, then bijective XCD chunking (m204)
  int bx = blockIdx.x, by = blockIdx.y;
  {
    const int gy = gridDim.y;
    const int nwg = gridDim.x * gy;
    const int id = bx * gy + by;
    const int q = nwg >> 3, r = nwg & 7;
    const int xcd = id & 7, pos = id >> 3;
    const int nid = ((xcd < r) ? xcd * (q + 1) : r * (q + 1) + (xcd - r) * q) + pos;
    bx = nid / gy; by = nid % gy;
  }

  int e = 0, sk = 0, zb = 0, zh = 0, cnte = 0, lsb = 0;
  if constexpr (GATHER != 0) {
    e = gmap[by];
    if (e < 0) return;
    cnte = gcnt[e];
    lsb = by * BM - gaoff[e];
    if constexpr (SPLITK > 1) sk = blockIdx.z;
  } else if constexpr (SPLITK > 1) {
    sk = blockIdx.z;
  } else {
    zb = blockIdx.z >> 4; zh = blockIdx.z & 15;
  }

  __shared__ __align__(16) u16 Ash[NSUB * BM * BK];
  __shared__ __align__(16) u16 Asl[(TERMS >= 2) ? NSUB * BM * BK : 8];
  __shared__ __align__(16) u16 Bsh[NSUB * BN * BK];
  __shared__ __align__(16) u16 Bsl[(TERMS == 3) ? NSUB * BN * BK : 8];

  const int tid = threadIdx.x;
  const int lane = tid & 63, wid = tid >> 6;

  const u16* Ab = A + (size_t)zb * offA_hi + (size_t)zh * offA_lo
                    + (GATHER == 1 ? 0 : (size_t)(by * BM) * lda);
  const u16* Bb = (const u16*)Bv + (size_t)zb * offB_hi + (size_t)zh * offB_lo
                    + (size_t)(bx * BN) * ldb;
  const float* Bfb = (const float*)Bv + (size_t)e * offB_hi
                    + (size_t)(bx * BN) * ldb;

  int grow[A_INST];
  if constexpr (GATHER == 1) {
#pragma unroll
    for (int j = 0; j < A_INST; ++j) {
      int ee = (j * 256 + tid) * 8;
      int sl = lsb + (ee >> 5);
      grow[j] = (sl < cnte) ? (glist[e * 2048 + sl] >> 1) : 0;
    }
  }

  const int wm0 = (wid / WGN) * WM;
  const int wn0 = (wid % WGN) * WN;
  const int fr = lane & 15;
  const int kb = (lane >> 4) * 8;

  f32x4 acc[FM][FN] = {};

  const int Ksp = K / SPLITK;
  const int kbeg = sk * Ksp, kend = kbeg + Ksp;
  for (int k0 = kbeg; k0 < kend; k0 += KSTEP) {
    __syncthreads();
#pragma unroll
    for (int s = 0; s < NSUB; ++s) {
      const int ks = k0 + s * BK;
      u16* AshS = Ash + s * BM * BK;
      u16* AslS = Asl + (TERMS >= 2 ? s * BM * BK : 0);
      u16* BshS = Bsh + s * BN * BK;
      u16* BslS = Bsl + (TERMS == 3 ? s * BN * BK : 0);
#pragma unroll
      for (int j = 0; j < A_INST; ++j) {
        int ee = (j * 256 + tid) * 8;
        size_t gs = (GATHER == 1 ? (size_t)grow[j] : (size_t)(ee >> 5)) * lda + ks + (ee & 31);
        gload_lds16(Ab + gs, (char*)AshS + (size_t)ee * 2);
        if constexpr (TERMS >= 2)
          gload_lds16(Ab + planeA + gs, (char*)AslS + (size_t)ee * 2);
      }
      if constexpr (BF32) {
#pragma unroll
        for (int j = 0; j < BF_INST; ++j) {
          int ee = (j * 256 + tid) * 4;
          float4 v = *(const float4*)(Bfb + (size_t)(ee >> 5) * ldb + ks + (ee & 31));
          uint2 hi, lo;
          split4(v, hi, lo);
          *(uint2*)&BshS[ee] = hi;
          if constexpr (TERMS == 3) *(uint2*)&BslS[ee] = lo;
        }
      } else {
#pragma unroll
        for (int j = 0; j < B_INST; ++j) {
          int ee = (j * 256 + tid) * 8;
          size_t gs = (size_t)(ee >> 5) * ldb + ks + (ee & 31);
          gload_lds16(Bb + gs, (char*)BshS + (size_t)ee * 2);
          if constexpr (TERMS == 3)
            gload_lds16(Bb + planeB + gs, (char*)BslS + (size_t)ee * 2);
        }
      }
    }
    __syncthreads();

#pragma unroll
    for (int s = 0; s < NSUB; ++s) {
      const u16* AshS = Ash + s * BM * BK;
      const u16* AslS = Asl + (TERMS >= 2 ? s * BM * BK : 0);
      const u16* BshS = Bsh + s * BN * BK;
      const u16* BslS = Bsl + (TERMS == 3 ? s * BN * BK : 0);
      short8 ah[FM], al_[FM], bh[FN], bl[FN];
#pragma unroll
      for (int mi = 0; mi < FM; ++mi) {
        int off = (wm0 + mi * 16 + fr) * BK + kb;
        ah[mi] = *(const short8*)&AshS[off];
        if constexpr (TERMS >= 2) al_[mi] = *(const short8*)&AslS[off];
      }
#pragma unroll
      for (int ni = 0; ni < FN; ++ni) {
        int off = (wn0 + ni * 16 + fr) * BK + kb;
        bh[ni] = *(const short8*)&BshS[off];
        if constexpr (TERMS == 3) bl[ni] = *(const short8*)&BslS[off];
      }
#pragma unroll
      for (int mi = 0; mi < FM; ++mi)
#pragma unroll
        for (int ni = 0; ni < FN; ++ni) {
          acc[mi][ni] = __builtin_amdgcn_mfma_f32_16x16x32_bf16(ah[mi], bh[ni], acc[mi][ni], 0, 0, 0);
          if constexpr (TERMS == 3)
            acc[mi][ni] = __builtin_amdgcn_mfma_f32_16x16x32_bf16(ah[mi], bl[ni], acc[mi][ni], 0, 0, 0);
          if constexpr (TERMS >= 2)
            acc[mi][ni] = __builtin_amdgcn_mfma_f32_16x16x32_bf16(al_[mi], bh[ni], acc[mi][ni], 0, 0, 0);
        }
    }
  }
  __syncthreads();

  const size_t offC = (size_t)zb * offC_hi + (size_t)zh * offC_lo;
  const int row0 = by * BM + wm0 + (lane >> 4) * 4;
  const int col0 = bx * BN + wn0 + fr;
  const float* biasp = bias ? bias + (size_t)e * offBias : nullptr;
  const bool addBias = biasp && (SPLITK == 1 || sk == 0);

#pragma unroll
  for (int mi = 0; mi < FM; ++mi) {
#pragma unroll
    for (int ni = 0; ni < FN; ++ni) {
      const int col = col0 + ni * 16;
      const float bv = addBias ? biasp[col] : 0.f;
#pragma unroll
      for (int r = 0; r < 4; ++r) {
        const int row = row0 + mi * 16 + r;
        float v = acc[mi][ni][r] * alpha + bv;
        if constexpr (GELU) v = 0.5f * v * (1.f + erff(v * 0.70710678118f));
        if constexpr (OUTMODE == 4) {
          int sl = row - gaoff[e];
          if (sl < cnte) {
            int lv = glist[e * 2048 + sl];
            int tok = lv >> 1, rank = lv & 1;
            float* p = (float*)Cv + (size_t)rank * planeC + (size_t)tok * ldc + col;
            float out = wf[tok * 2 + rank] * v;
            if constexpr (SPLITK > 1) atomAddF(p, out); else *p = out;
          }
        } else {
          const size_t idx = offC + (size_t)row * ldc + col;
          if constexpr (OUTMODE == 1) {
            u16 hh = f2bf(v);
            u16 ll = f2bf(v - bf2f(hh));
            ((u16*)Cv)[idx] = hh;
            ((u16*)Cv)[idx + planeC] = ll;
          } else if constexpr (OUTMODE == 3) {
            if constexpr (SPLITK > 1) atomAddF((float*)Cv + idx, v);
            else ((float*)Cv)[idx] += v;
          } else {
            ((float*)Cv)[idx] = v;
          }
        }
      }
    }
  }
}

// ---------------------------------------------------------------------------
// Fused attention: ctx = softmax(q k^T / 8) @ v, one block per (bh, 128-q-tile)
// (verified round-9 structure, unchanged)
// ---------------------------------------------------------------------------
__global__ __launch_bounds__(512)
void attn_fused(const u16* __restrict__ qkv, long planeQ,
                const u16* __restrict__ vT, long planeV,
                u16* __restrict__ ctxs, long planeC)
{
  constexpr int BK = 32, S = 512;
  extern __shared__ __align__(16) char smem[];
  u16* Ash = (u16*)smem;
  u16* Asl = Ash + 128 * 32;
  u16* Bsh = Asl + 128 * 32;
  u16* Bsl = Bsh + 512 * 32;
  float* redM = (float*)(Bsl + 512 * 32);
  float* redS = redM + 512;
  u16* Ph = (u16*)smem;
  u16* Pl = Ph + 128 * 32;
  u16* Vh = Pl + 128 * 32;
  u16* Vl = Vh + 64 * 32;

  const int tid = threadIdx.x, lane = tid & 63, wid = tid >> 6;
  const int bh = blockIdx.z, zb = bh >> 4, zh = bh & 15;
  const int qt = blockIdx.y;
  const u16* Ab = qkv + (size_t)zb * (512 * 3072) + (size_t)zh * 64
                      + (size_t)(qt * 128) * 3072;
  const u16* Bb = qkv + (size_t)zb * (512 * 3072) + (size_t)zh * 64 + 1024;
  const u16* vt = vT + (size_t)bh * (64 * 512);

  const int wr = wid >> 2, wc = wid & 3;
  const int fr = lane & 15, kb = (lane >> 4) * 8, g = lane >> 4;

  f32x4 acc[4][8] = {};

  for (int k0 = 0; k0 < 64; k0 += BK) {
    __syncthreads();
    {
      int ee = tid * 8;
      size_t gs = (size_t)(ee >> 5) * 3072 + k0 + (ee & 31);
      gload_lds16(Ab + gs,          (char*)Ash + (size_t)ee * 2);
      gload_lds16(Ab + planeQ + gs, (char*)Asl + (size_t)ee * 2);
    }
#pragma unroll
    for (int j = 0; j < 4; ++j) {
      int ee = (j * 512 + tid) * 8;
      size_t gs = (size_t)(ee >> 5) * 3072 + k0 + (ee & 31);
      gload_lds16(Bb + gs,          (char*)Bsh + (size_t)ee * 2);
      gload_lds16(Bb + planeQ + gs, (char*)Bsl + (size_t)ee * 2);
    }
    __syncthreads();

    short8 ah[4], al_[4];
#pragma unroll
    for (int mi = 0; mi < 4; ++mi) {
      int off = (wr * 64 + mi * 16 + fr) * BK + kb;
      ah[mi]  = *(const short8*)&Ash[off];
      al_[mi] = *(const short8*)&Asl[off];
    }
#pragma unroll
    for (int ni = 0; ni < 8; ++ni) {
      int off = (wc * 128 + ni * 16 + fr) * BK + kb;
      short8 bhv = *(const short8*)&Bsh[off];
      short8 blv = *(const short8*)&Bsl[off];
#pragma unroll
      for (int mi = 0; mi < 4; ++mi) {
        acc[mi][ni] = __builtin_amdgcn_mfma_f32_16x16x32_bf16(ah[mi],  bhv, acc[mi][ni], 0, 0, 0);
        acc[mi][ni] = __builtin_amdgcn_mfma_f32_16x16x32_bf16(ah[mi],  blv, acc[mi][ni], 0, 0, 0);
        acc[mi][ni] = __builtin_amdgcn_mfma_f32_16x16x32_bf16(al_[mi], bhv, acc[mi][ni], 0, 0, 0);
      }
    }
  }

#pragma unroll
  for (int mi = 0; mi < 4; ++mi)
#pragma unroll
    for (int ni = 0; ni < 8; ++ni)
#pragma unroll
      for (int r = 0; r < 4; ++r) acc[mi][ni][r] *= 0.125f;

  float m[4][4];
#pragma unroll
  for (int mi = 0; mi < 4; ++mi)
#pragma unroll
    for (int r = 0; r < 4; ++r) {
      float v = acc[mi][0][r];
#pragma unroll
      for (int ni = 1; ni < 8; ++ni) v = fmaxf(v, acc[mi][ni][r]);
      v = fmaxf(v, __shfl_xor(v, 1));
      v = fmaxf(v, __shfl_xor(v, 2));
      v = fmaxf(v, __shfl_xor(v, 4));
      v = fmaxf(v, __shfl_xor(v, 8));
      m[mi][r] = v;
    }
  if (fr == 0) {
#pragma unroll
    for (int mi = 0; mi < 4; ++mi)
#pragma unroll
      for (int r = 0; r < 4; ++r)
        redM[wr * 256 + (g * 4 + mi * 16 + r) * 4 + wc] = m[mi][r];
  }
  __syncthreads();
#pragma unroll
  for (int mi = 0; mi < 4; ++mi)
#pragma unroll
    for (int r = 0; r < 4; ++r) {
      const float* p = &redM[wr * 256 + (g * 4 + mi * 16 + r) * 4];
      m[mi][r] = fmaxf(fmaxf(p[0], p[1]), fmaxf(p[2], p[3]));
    }

  float ssum[4][4];
#pragma unroll
  for (int mi = 0; mi < 4; ++mi)
#pragma unroll
    for (int r = 0; r < 4; ++r) {
      float ss = 0.f;
#pragma unroll
      for (int ni = 0; ni < 8; ++ni) {
        float p = __expf(acc[mi][ni][r] - m[mi][r]);
        acc[mi][ni][r] = p;
        ss += p;
      }
      ss += __shfl_xor(ss, 1);
      ss += __shfl_xor(ss, 2);
      ss += __shfl_xor(ss, 4);
      ss += __shfl_xor(ss, 8);
      ssum[mi][r] = ss;
    }
  if (fr == 0) {
#pragma unroll
    for (int mi = 0; mi < 4; ++mi)
#pragma unroll
      for (int r = 0; r < 4; ++r)
        redS[wr * 256 + (g * 4 + mi * 16 + r) * 4 + wc] = ssum[mi][r];
  }
  __syncthreads();

#pragma unroll
  for (int mi = 0; mi < 4; ++mi)
#pragma unroll
    for (int r = 0; r < 4; ++r) {
      const float* p = &redS[wr * 256 + (g * 4 + mi * 16 + r) * 4];
      const float inv = 1.f / (p[0] + p[1] + p[2] + p[3]);
#pragma unroll
      for (int ni = 0; ni < 8; ++ni) acc[mi][ni][r] *= inv;
    }

  f32x4 c[4] = {};
#pragma unroll
  for (int ks = 0; ks < 16; ++ks) {
    const int k0 = ks * 32;
    __syncthreads();
    if (wc == (ks >> 2)) {
      const int ni0 = (ks & 3) * 2;
#pragma unroll
      for (int mi = 0; mi < 4; ++mi)
#pragma unroll
        for (int dni = 0; dni < 2; ++dni)
#pragma unroll
          for (int r = 0; r < 4; ++r) {
            float v = acc[mi][ni0 + dni][r];
            u16 h = f2bf(v);
            u16 lo = f2bf(v - bf2f(h));
            int row = wr * 64 + mi * 16 + g * 4 + r;
            int koff = dni * 16 + fr;
            Ph[row * 32 + koff] = h;
            Pl[row * 32 + koff] = lo;
          }
    }
    {
      int ee = (tid & 255) * 8;
      size_t gs = (size_t)(ee >> 5) * 512 + k0 + (ee & 31);
      if (tid < 256) gload_lds16(vt + gs,          (char*)Vh + (size_t)ee * 2);
      else           gload_lds16(vt + planeV + gs, (char*)Vl + (size_t)ee * 2);
    }
    __syncthreads();

    short8 pah = *(const short8*)&Ph[(wid * 16 + fr) * 32 + kb];
    short8 pal = *(const short8*)&Pl[(wid * 16 + fr) * 32 + kb];
#pragma unroll
    for (int ni = 0; ni < 4; ++ni) {
      short8 vbh = *(const short8*)&Vh[(ni * 16 + fr) * 32 + kb];
      short8 vbl = *(const short8*)&Vl[(ni * 16 + fr) * 32 + kb];
      c[ni] = __builtin_amdgcn_mfma_f32_16x16x32_bf16(pah, vbh, c[ni], 0, 0, 0);
      c[ni] = __builtin_amdgcn_mfma_f32_16x16x32_bf16(pah, vbl, c[ni], 0, 0, 0);
      c[ni] = __builtin_amdgcn_mfma_f32_16x16x32_bf16(pal, vbh, c[ni], 0, 0, 0);
    }
  }

#pragma unroll
  for (int ni = 0; ni < 4; ++ni)
#pragma unroll
    for (int r = 0; r < 4; ++r) {
      int row = qt * 128 + wid * 16 + g * 4 + r;
      int d = ni * 16 + fr;
      size_t idx = ((size_t)zb * 512 + row) * 1024 + zh * 64 + d;
      float v = c[ni][r];
      u16 h = f2bf(v);
      u16 lo = f2bf(v - bf2f(h));
      ctxs[idx] = h;
      ctxs[idx + planeC] = lo;
    }
}

// ---------------------------------------------------------------------------
__global__ __launch_bounds__(256)
void embed_kernel(const int* __restrict__ ids, const float* __restrict__ tok,
                  const float* __restrict__ pos, float* __restrict__ x,
                  u16* __restrict__ xs, long plane)
{
  const int t = blockIdx.x, c = threadIdx.x;
  const int id = ids[t], s = t & 511;
  float4 tv = ((const float4*)(tok + (size_t)id * 1024))[c];
  float4 pv = ((const float4*)(pos + (size_t)s * 1024))[c];
  float o[4] = {tv.x + pv.x, tv.y + pv.y, tv.z + pv.z, tv.w + pv.w};
  ((float4*)(x + (size_t)t * 1024))[c] = *(float4*)o;
  uint2 uh, ul;
  u16 h0 = f2bf(o[0]), h1 = f2bf(o[1]), h2 = f2bf(o[2]), h3 = f2bf(o[3]);
  uh.x = (unsigned)h0 | ((unsigned)h1 << 16);
  uh.y = (unsigned)h2 | ((unsigned)h3 << 16);
  ul.x = (unsigned)f2bf(o[0] - bf2f(h0)) | ((unsigned)f2bf(o[1] - bf2f(h1)) << 16);
  ul.y = (unsigned)f2bf(o[2] - bf2f(h2)) | ((unsigned)f2bf(o[3] - bf2f(h3)) << 16);
  const size_t idx = (size_t)t * 1024 + c * 4;
  *(uint2*)(xs + idx) = uh;
  *(uint2*)(xs + plane + idx) = ul;
}

// ---------------------------------------------------------------------------
__global__ __launch_bounds__(256)
void ln_kernel(float* __restrict__ x, const float* __restrict__ g,
               const float* __restrict__ b, u16* __restrict__ xs, long plane)
{
  const int row = blockIdx.x, t = threadIdx.x;
  float4 xv = ((const float4*)(x + (size_t)row * 1024))[t];
  float s = xv.x + xv.y + xv.z + xv.w;
  float q = xv.x * xv.x + xv.y * xv.y + xv.z * xv.z + xv.w * xv.w;
#pragma unroll
  for (int o = 32; o; o >>= 1) { s += __shfl_xor(s, o); q += __shfl_xor(q, o); }
  __shared__ float ss[4], qq[4];
  const int wid = t >> 6;
  if ((t & 63) == 0) { ss[wid] = s; qq[wid] = q; }
  __syncthreads();
  s = ss[0] + ss[1] + ss[2] + ss[3];
  q = qq[0] + qq[1] + qq[2] + qq[3];
  const float mean = s * (1.f / 1024.f);
  const float var = q * (1.f / 1024.f) - mean * mean;
  const float rstd = 1.f / sqrtf(var + 1e-5f);
  float4 gv = ((const float4*)g)[t];
  float4 bv = ((const float4*)b)[t];
  float o[4];
  o[0] = (xv.x - mean) * rstd * gv.x + bv.x;
  o[1] = (xv.y - mean) * rstd * gv.y + bv.y;
  o[2] = (xv.z - mean) * rstd * gv.z + bv.z;
  o[3] = (xv.w - mean) * rstd * gv.w + bv.w;
  ((float4*)(x + (size_t)row * 1024))[t] = *(float4*)o;
  uint2 uh, ul;
  u16 h0 = f2bf(o[0]), h1 = f2bf(o[1]), h2 = f2bf(o[2]), h3 = f2bf(o[3]);
  uh.x = (unsigned)h0 | ((unsigned)h1 << 16);
  uh.y = (unsigned)h2 | ((unsigned)h3 << 16);
  ul.x = (unsigned)f2bf(o[0] - bf2f(h0)) | ((unsigned)f2bf(o[1] - bf2f(h1)) << 16);
  ul.y = (unsigned)f2bf(o[2] - bf2f(h2)) | ((unsigned)f2bf(o[3] - bf2f(h3)) << 16);
  const size_t idx = (size_t)row * 1024 + t * 4;
  *(uint2*)(xs + idx) = uh;
  *(uint2*)(xs + plane + idx) = ul;
}

// ---------------------------------------------------------------------------
// V transpose on both planes: vT[bh][d][s] = qkv[b*512+s][2048+h*64+d]
// ---------------------------------------------------------------------------
__global__ __launch_bounds__(256)
void vtrans_kernel(const u16* __restrict__ qkv, u16* __restrict__ vT,
                   long planeQ, long planeV)
{
  __shared__ u16 tile[64][68];
  const u16* src = qkv + (size_t)blockIdx.z * planeQ;
  u16* dst = vT + (size_t)blockIdx.z * planeV;
  const int s0 = blockIdx.x << 6;
  const int bh = blockIdx.y, b = bh >> 4, h = bh & 15;
  const int t = threadIdx.x;
#pragma unroll
  for (int j = 0; j < 16; ++j) {
    int idx = j * 256 + t;
    int sl = idx >> 6, d = idx & 63;
    tile[sl][d] = src[(size_t)(b * 512 + s0 + sl) * 3072 + 2048 + h * 64 + d];
  }
  __syncthreads();
#pragma unroll
  for (int j = 0; j < 16; ++j) {
    int idx = j * 256 + t;
    int d = idx >> 6, sl = idx & 63;
    dst[(size_t)bh * (64 * 512) + (size_t)d * 512 + s0 + sl] = tile[sl][d];
  }
}

// ---------------------------------------------------------------------------
__global__ __launch_bounds__(256)
void router_kernel(const float* __restrict__ x, const float* __restrict__ Wr,
                   const float* __restrict__ br, int2* __restrict__ er,
                   float2* __restrict__ wf)
{
  const int lane = threadIdx.x & 63, wid = threadIdx.x >> 6;
  const int t = blockIdx.x * 4 + wid;
  const float* xr = x + (size_t)t * 1024;
  float xv[16];
#pragma unroll
  for (int j = 0; j < 16; ++j) xv[j] = xr[j * 64 + lane];
  float p[8];
#pragma unroll
  for (int e = 0; e < 8; ++e) {
    const float* wr = Wr + (size_t)e * 1024;
    float s = 0.f;
#pragma unroll
    for (int j = 0; j < 16; ++j) s += xv[j] * wr[j * 64 + lane];
#pragma unroll
    for (int o = 32; o; o >>= 1) s += __shfl_xor(s, o);
    p[e] = s + br[e];
  }
  float m = p[0];
#pragma unroll
  for (int e = 1; e < 8; ++e) m = fmaxf(m, p[e]);
#pragma unroll
  for (int e = 0; e < 8; ++e) p[e] = __expf(p[e] - m);
  int i1 = -1; float v1 = -1.f;
#pragma unroll
  for (int e = 0; e < 8; ++e) if (p[e] > v1) { v1 = p[e]; i1 = e; }
  int i2 = -1; float v2 = -1.f;
#pragma unroll
  for (int e = 0; e < 8; ++e) if (e != i1 && p[e] > v2) { v2 = p[e]; i2 = e; }
  const float inv = 1.f / (v1 + v2);
  if (lane == 0) {
    er[t] = make_int2(i1, i2);
    wf[t] = make_float2(v1 * inv, v2 * inv);
  }
}

// ---------------------------------------------------------------------------
__global__ __launch_bounds__(256)
void build_lists(const int2* __restrict__ er, int* __restrict__ cnt,
                 int* __restrict__ list)
{
  const int t = blockIdx.x * 256 + threadIdx.x;
  int2 e = er[t];
  int s0 = atomicAdd(&cnt[e.x], 1); list[e.x * 2048 + s0] = t * 2;
  int s1 = atomicAdd(&cnt[e.y], 1); list[e.y * 2048 + s1] = t * 2 + 1;
}

// ---------------------------------------------------------------------------
__global__ void finalize_lists(const int* __restrict__ cnt, int* __restrict__ aoff,
                               int* __restrict__ block2e, int nb)
{
  if (threadIdx.x != 0 || blockIdx.x != 0) return;
  for (int b = 0; b < nb; ++b) block2e[b] = -1;
  int off = 0;
  for (int e = 0; e < 8; ++e) {
    aoff[e] = off;
    int pe = ((cnt[e] + 127) >> 7) << 7;
    for (int b = off >> 7; b < (off + pe) >> 7; ++b) block2e[b] = e;
    off += pe;
  }
  aoff[8] = off;
}

// ---------------------------------------------------------------------------
__global__ __launch_bounds__(256)
void combine_split(const float* __restrict__ o0, const float* __restrict__ o1,
                   u16* __restrict__ dh, long plane)
{
  const long i = ((long)blockIdx.x * 256 + threadIdx.x) * 8;
  float4 a0 = ((const float4*)o0)[i / 4];
  float4 a1 = ((const float4*)o0)[i / 4 + 1];
  float4 b0 = ((const float4*)o1)[i / 4];
  float4 b1 = ((const float4*)o1)[i / 4 + 1];
  float v[8] = {a0.x + b0.x, a0.y + b0.y, a0.z + b0.z, a0.w + b0.w,
                a1.x + b1.x, a1.y + b1.y, a1.z + b1.z, a1.w + b1.w};
  u16 h[8], l[8];
#pragma unroll
  for (int j = 0; j < 8; ++j) {
    h[j] = f2bf(v[j]);
    l[j] = f2bf(v[j] - bf2f(h[j]));
  }
  uint4 uh, ul;
  uh.x = (unsigned)h[0] | ((unsigned)h[1] << 16); ul.x = (unsigned)l[0] | ((unsigned)l[1] << 16);
  uh.y = (unsigned)h[2] | ((unsigned)h[3] << 16); ul.y = (unsigned)l[2] | ((unsigned)l[3] << 16);
  uh.z = (unsigned)h[4] | ((unsigned)h[5] << 16); ul.z = (unsigned)l[4] | ((unsigned)l[5] << 16);
  uh.w = (unsigned)h[6] | ((unsigned)h[7] << 16); ul.w = (unsigned)l[6] | ((unsigned)l[7] << 16);
  ((uint4*)dh)[i / 8] = uh;
  ((uint4*)(dh + plane))[i / 8] = ul;
}

// ---------------------------------------------------------------------------
__global__ __launch_bounds__(256)
void trunc_bf16(const float* __restrict__ s, u16* __restrict__ d)
{
  const long i = ((long)blockIdx.x * 256 + threadIdx.x) * 8;
  float4 a = ((const float4*)s)[i / 4];
  float4 b = ((const float4*)s)[i / 4 + 1];
  uint4 u;
  u.x = (unsigned)f2bf(a.x) | ((unsigned)f2bf(a.y) << 16);
  u.y = (unsigned)f2bf(a.z) | ((unsigned)f2bf(a.w) << 16);
  u.z = (unsigned)f2bf(b.x) | ((unsigned)f2bf(b.y) << 16);
  u.w = (unsigned)f2bf(b.z) | ((unsigned)f2bf(b.w) << 16);
  ((uint4*)d)[i / 8] = u;
}

// ---------------------------------------------------------------------------

extern "C" void kernel_launch(void* const* d_in, const int* in_sizes, int n_in,
                              void* d_out, int out_size, void* d_ws, size_t ws_size,
                              hipStream_t stream)
{
  (void)in_sizes; (void)n_in; (void)out_size;
  const int*   ids  = (const int*)d_in[0];
  const float* tok  = (const float*)d_in[2];
  const float* pos  = (const float*)d_in[3];
  const float* Wqkv = (const float*)d_in[4];
  const float* bqkv = (const float*)d_in[5];
  const float* Wo   = (const float*)d_in[6];
  const float* bo   = (const float*)d_in[7];
  const float* ln1g = (const float*)d_in[8];
  const float* ln1b = (const float*)d_in[9];
  const float* ln2g = (const float*)d_in[10];
  const float* ln2b = (const float*)d_in[11];
  const float* W1   = (const float*)d_in[12];
  const float* b1   = (const float*)d_in[13];
  const float* W2   = (const float*)d_in[14];
  const float* b2   = (const float*)d_in[15];
  const float* Wr   = (const float*)d_in[16];
  const float* br   = (const float*)d_in[17];
  const float* We1  = (const float*)d_in[18];
  const float* be1  = (const float*)d_in[19];
  const float* We2  = (const float*)d_in[20];
  const float* be2  = (const float*)d_in[21];
  const float* Wout = (const float*)d_in[22];
  const float* bout = (const float*)d_in[23];

  constexpr int T = 2048, D = 1024, S = 512, Bb = 4, H = 16, dh = 64, F = 4096,
                L = 12, E = 8, V = 32000;
  constexpr int NB = (2 * T + E * 127) / 128 + 1;   // padded slot blocks (40)

  constexpr long PX  = (long)T * D;
  constexpr long PQ  = (long)T * 3 * D;
  constexpr long PFE = (long)(NB * 128) * F;        // padded expert hidden
  constexpr long PV  = (long)Bb * H * dh * S;

  char* w = (char*)d_ws;
  size_t o = 0;
  auto alloc = [&](size_t bytes) -> void* {
    void* p = w + o; o = (o + bytes + 255) & ~(size_t)255; return p;
  };
  float* x    = (float*)alloc((size_t)T * D * 4);
  u16* xs   = (u16*)alloc((size_t)2 * PX * 2);
  u16* moes = (u16*)alloc((size_t)2 * PX * 2);
  u16* qkvs = (u16*)alloc((size_t)2 * PQ * 2);
  u16* ctxs = (u16*)alloc((size_t)2 * PX * 2);
  u16* ffs  = (u16*)alloc((size_t)2 * PFE * 2);
  u16* vTs  = (u16*)alloc((size_t)2 * PV * 2);
  u16* woutb = (u16*)alloc((size_t)V * D * 2);
  float* outr = (float*)alloc((size_t)2 * PX * 4);
  int2*   er  = (int2*)alloc((size_t)T * 8);
  float2* wf  = (float2*)alloc((size_t)T * 8);
  int*    cnt = (int*)alloc((size_t)E * 4);
  int*    list= (int*)alloc((size_t)E * T * 4);
  int*    aoff= (int*)alloc((size_t)(E + 1) * 4);
  int*    b2e = (int*)alloc((size_t)NB * 4);
  if (o > ws_size) return;  // output stays poisoned -> visible failure

  embed_kernel<<<T, 256, 0, stream>>>(ids, tok, pos, x, xs, PX);
  trunc_bf16<<<(V * D) / 2048, 256, 0, stream>>>(Wout, woutb);

  constexpr size_t ATTN_LDS = (4096 + 4096 + 16384 + 16384) * 2 + 2 * 512 * 4;

  for (int l = 0; l < L; ++l) {
    // qkv = xs @ Wqkv^T + bqkv -> split qkvs
    gemm_bt<128,128,2,2,1,false,0,true,1,3>
        <<<dim3(3 * D / 128, T / 128, 1), 256, 0, stream>>>(
        xs, D, PX, 0, 0, Wqkv + (size_t)l * 3 * D * D, D, 0, 0, 0,
        qkvs, 3 * D, PQ, 0, 0, D, 1.f, bqkv + (size_t)l * 3 * D, 0,
        nullptr, nullptr, nullptr, nullptr, nullptr);
    vtrans_kernel<<<dim3(S / 64, Bb * H, 2), 256, 0, stream>>>(qkvs, vTs, PQ, PV);
    // ctx = softmax(q k^T / 8) @ v  (fused)
    attn_fused<<<dim3(1, S / 128, Bb * H), 512, ATTN_LDS, stream>>>(
        qkvs, PQ, vTs, PV, ctxs, PX);
    // x += ctx @ Wo^T + bo   (split-K=2, atomic f32)
    gemm_bt<128,128,2,2,3,false,0,true,2,3>
        <<<dim3(D / 128, T / 128, 2), 256, 0, stream>>>(
        ctxs, D, PX, 0, 0, Wo + (size_t)l * D * D, D, 0, 0, 0,
        x, D, 0, 0, 0, D, 1.f, bo + (size_t)l * D, 0,
        nullptr, nullptr, nullptr, nullptr, nullptr);
    ln_kernel<<<T, 256, 0, stream>>>(x, ln1g + (size_t)l * D, ln1b + (size_t)l * D, xs, PX);
    // ff = gelu(xs @ W1^T + b1) -> split ffs
    gemm_bt<128,128,2,2,1,true,0,true,1,3>
        <<<dim3(F / 128, T / 128, 1), 256, 0, stream>>>(
        xs, D, PX, 0, 0, W1 + (size_t)l * F * D, D, 0, 0, 0,
        ffs, F, (long)T * F, 0, 0, D, 1.f, b1 + (size_t)l * F, 0,
        nullptr, nullptr, nullptr, nullptr, nullptr);
    // x += ffs @ W2^T + b2   (split-K=4, atomic f32)
    gemm_bt<128,128,2,2,3,false,0,true,4,3>
        <<<dim3(D / 128, T / 128, 4), 256, 0, stream>>>(
        ffs, F, (long)T * F, 0, 0, W2 + (size_t)l * D * F, F, 0, 0, 0,
        x, D, 0, 0, 0, F, 1.f, b2 + (size_t)l * D, 0,
        nullptr, nullptr, nullptr, nullptr, nullptr);
    ln_kernel<<<T, 256, 0, stream>>>(x, ln2g + (size_t)l * D, ln2b + (size_t)l * D, xs, PX);
  }

  // ---- sparse top-2 MoE (batched experts via 128-padded slot blocks) ----
  router_kernel<<<T / 4, 256, 0, stream>>>(x, Wr, br, er, wf);
  hipMemsetAsync(cnt, 0, E * 4, stream);
  build_lists<<<T / 256, 256, 0, stream>>>(er, cnt, list);
  finalize_lists<<<1, 64, 0, stream>>>(cnt, aoff, b2e, NB);
  hipMemsetAsync(outr, 0, (size_t)2 * PX * 4, stream);

  gemm_bt<128,128,2,2,1,true,1,true,1,2>
      <<<dim3(F / 128, NB, 1), 256, 0, stream>>>(
      xs, D, PX, 0, 0, We1, D, 0, (long)F * D, 0,
      ffs, F, PFE, 0, 0, D, 1.f, be1, F,
      nullptr, list, cnt, b2e, aoff);
  gemm_bt<128,128,2,2,4,false,2,true,2,2>
      <<<dim3(D / 128, NB, 2), 256, 0, stream>>>(
      ffs, F, PFE, 0, 0, We2, F, 0, (long)D * F, 0,
      outr, D, PX, 0, 0, F, 1.f, be2, D,
      (const float*)wf, list, cnt, b2e, aoff);

  combine_split<<<(PX / 2048), 256, 0, stream>>>(outr, outr + PX, moes, PX);

  // logits = moes(hi) @ Wout(bf16)^T + bout -> f32 d_out
  // 1-term 128x128, NSUB=2: 32 MFMA per barrier pair, 64B LDS sub-buffer
  // stride (conflict-free), acc unchanged (occupancy preserved).
  gemm_bt<128,128,2,2,0,false,0,false,1,1,2>
      <<<dim3(V / 128, T / 128, 1), 256, 0, stream>>>(
      moes, D, PX, 0, 0, woutb, D, 0, 0, 0,
      (float*)d_out, V, 0, 0, 0,
      D, 1.f, bout, 0, nullptr, nullptr, nullptr, nullptr, nullptr);
}

// Round 14
// 4334.214 us; speedup vs baseline: 1.0388x; 1.0005x over previous
//
#include <hip/hip_runtime.h>
#include <cstdint>
#include <cstddef>

#define DI __device__ __forceinline__

typedef __attribute__((ext_vector_type(8))) short short8;   // 8 bf16 = 4 VGPR (MFMA A/B frag)
typedef __attribute__((ext_vector_type(4))) float f32x4;    // MFMA C/D frag
typedef unsigned short u16;

DI u16 f2bf(float f) {
  union { float f; unsigned u; } v; v.f = f;
  unsigned r = v.u + 0x7fffu + ((v.u >> 16) & 1u);  // RNE
  return (u16)(r >> 16);
}
DI float bf2f(u16 h) {
  union { unsigned u; float f; } v; v.u = ((unsigned)h) << 16;
  return v.f;
}

DI void gload_lds16(const void* g, void* l) {
  __builtin_amdgcn_global_load_lds(
      (const __attribute__((address_space(1))) void*)g,
      (__attribute__((address_space(3))) void*)l, 16, 0, 0);
}

DI void atomAddF(float* p, float v) {
  __hip_atomic_fetch_add(p, v, __ATOMIC_RELAXED, __HIP_MEMORY_SCOPE_AGENT);
}

// split 4 f32 -> packed hi (RNE) and lo (trunc of exact residual) bf16 pairs
DI void split4(float4 v, uint2& hi, uint2& lo) {
  unsigned u0 = __float_as_uint(v.x), u1 = __float_as_uint(v.y);
  unsigned u2 = __float_as_uint(v.z), u3 = __float_as_uint(v.w);
  unsigned r0 = (u0 + 0x7fffu + ((u0 >> 16) & 1u)) & 0xffff0000u;
  unsigned r1 = (u1 + 0x7fffu + ((u1 >> 16) & 1u)) & 0xffff0000u;
  unsigned r2 = (u2 + 0x7fffu + ((u2 >> 16) & 1u)) & 0xffff0000u;
  unsigned r3 = (u3 + 0x7fffu + ((u3 >> 16) & 1u)) & 0xffff0000u;
  unsigned l0 = __float_as_uint(v.x - __uint_as_float(r0));
  unsigned l1 = __float_as_uint(v.y - __uint_as_float(r1));
  unsigned l2 = __float_as_uint(v.z - __uint_as_float(r2));
  unsigned l3 = __float_as_uint(v.w - __uint_as_float(r3));
  hi.x = __builtin_amdgcn_perm(r1, r0, 0x07060302u);
  hi.y = __builtin_amdgcn_perm(r3, r2, 0x07060302u);
  lo.x = __builtin_amdgcn_perm(l1, l0, 0x07060302u);
  lo.y = __builtin_amdgcn_perm(l3, l2, 0x07060302u);
}

// ---------------------------------------------------------------------------
// Split-bf16 emulated-f32 GEMM:  C = alpha * A(M,K) * B(N,K)^T (+bias)(GELU)
// A: two bf16 planes (hi at ptr, lo at ptr+planeA).
// B: BF32 -> raw f32, reg-staged + split in-register; else bf16 plane(s).
// TERMS: 3 = ah*bh + ah*bl + al*bh (~f32 fidelity, pre-router path);
//        2 = ah*bh + al*bh (post-router); 1 = ah*bh (LM head).
// NSUB: K-sub-tiles per barrier pair, each its own 8 KB LDS sub-buffer at
//   the conflict-free 64B row stride (r13: LM head 238->211 us, conflicts flat).
// OUTMODE: 0 f32 store, 1 split-bf16 store, 3 f32 C += v (atomic if SK>1),
//          4 MoE scatter. GATHER: 1 A-row gather, 2 epilogue scatter.
// ---------------------------------------------------------------------------
template<int BM, int BN, int WGM, int WGN, int OUTMODE, bool GELU, int GATHER,
         bool BF32, int SPLITK, int TERMS, int NSUB = 1>
__global__ __launch_bounds__(256)
void gemm_bt(const u16* __restrict__ A, int lda, long planeA, long offA_hi, long offA_lo,
             const void* __restrict__ Bv, int ldb, long planeB, long offB_hi, long offB_lo,
             void* __restrict__ Cv, int ldc, long planeC, long offC_hi, long offC_lo,
             int K, float alpha,
             const float* __restrict__ bias, long offBias,
             const float* __restrict__ wf,
             const int* __restrict__ glist,
             const int* __restrict__ gcnt,
             const int* __restrict__ gmap,
             const int* __restrict__ gaoff)
{
  constexpr int BK = 32;                 // per-sub-buffer K (64B stride)
  constexpr int KSTEP = BK * NSUB;
  constexpr int WM = BM / WGM, WN = BN / WGN;
  constexpr int FM = WM / 16, FN = WN / 16;
  constexpr int A_INST = (BM * BK) / (256 * 8);
  constexpr int B_INST = (BN * BK) / (256 * 8);
  constexpr int BF_INST = (BN * BK) / (256 * 4);
  static_assert(A_INST * 2048 == BM * BK && B_INST * 2048 == BN * BK, "tile sizing");

  // column-panel-contiguous linear id, then bijective XCD chunking (m204)
  int bx = blockIdx.x, by = blockIdx.y;
  {
    const int gy = gridDim.y;
    const int nwg = gridDim.x * gy;
    const int id = bx * gy + by;
    const int q = nwg >> 3, r = nwg & 7;
    const int xcd = id & 7, pos = id >> 3;
    const int nid = ((xcd < r) ? xcd * (q + 1) : r * (q + 1) + (xcd - r) * q) + pos;
    bx = nid / gy; by = nid % gy;
  }

  int e = 0, sk = 0, zb = 0, zh = 0, cnte = 0, lsb = 0;
  if constexpr (GATHER != 0) {
    e = gmap[by];
    if (e < 0) return;
    cnte = gcnt[e];
    lsb = by * BM - gaoff[e];
    if constexpr (SPLITK > 1) sk = blockIdx.z;
  } else if constexpr (SPLITK > 1) {
    sk = blockIdx.z;
  } else {
    zb = blockIdx.z >> 4; zh = blockIdx.z & 15;
  }

  __shared__ __align__(16) u16 Ash[NSUB * BM * BK];
  __shared__ __align__(16) u16 Asl[(TERMS >= 2) ? NSUB * BM * BK : 8];
  __shared__ __align__(16) u16 Bsh[NSUB * BN * BK];
  __shared__ __align__(16) u16 Bsl[(TERMS == 3) ? NSUB * BN * BK : 8];

  const int tid = threadIdx.x;
  const int lane = tid & 63, wid = tid >> 6;

  const u16* Ab = A + (size_t)zb * offA_hi + (size_t)zh * offA_lo
                    + (GATHER == 1 ? 0 : (size_t)(by * BM) * lda);
  const u16* Bb = (const u16*)Bv + (size_t)zb * offB_hi + (size_t)zh * offB_lo
                    + (size_t)(bx * BN) * ldb;
  const float* Bfb = (const float*)Bv + (size_t)e * offB_hi
                    + (size_t)(bx * BN) * ldb;

  int grow[A_INST];
  if constexpr (GATHER == 1) {
#pragma unroll
    for (int j = 0; j < A_INST; ++j) {
      int ee = (j * 256 + tid) * 8;
      int sl = lsb + (ee >> 5);
      grow[j] = (sl < cnte) ? (glist[e * 2048 + sl] >> 1) : 0;
    }
  }

  const int wm0 = (wid / WGN) * WM;
  const int wn0 = (wid % WGN) * WN;
  const int fr = lane & 15;
  const int kb = (lane >> 4) * 8;

  f32x4 acc[FM][FN] = {};

  const int Ksp = K / SPLITK;
  const int kbeg = sk * Ksp, kend = kbeg + Ksp;
  for (int k0 = kbeg; k0 < kend; k0 += KSTEP) {
    __syncthreads();
#pragma unroll
    for (int s = 0; s < NSUB; ++s) {
      const int ks = k0 + s * BK;
      u16* AshS = Ash + s * BM * BK;
      u16* AslS = Asl + (TERMS >= 2 ? s * BM * BK : 0);
      u16* BshS = Bsh + s * BN * BK;
      u16* BslS = Bsl + (TERMS == 3 ? s * BN * BK : 0);
#pragma unroll
      for (int j = 0; j < A_INST; ++j) {
        int ee = (j * 256 + tid) * 8;
        size_t gs = (GATHER == 1 ? (size_t)grow[j] : (size_t)(ee >> 5)) * lda + ks + (ee & 31);
        gload_lds16(Ab + gs, (char*)AshS + (size_t)ee * 2);
        if constexpr (TERMS >= 2)
          gload_lds16(Ab + planeA + gs, (char*)AslS + (size_t)ee * 2);
      }
      if constexpr (BF32) {
#pragma unroll
        for (int j = 0; j < BF_INST; ++j) {
          int ee = (j * 256 + tid) * 4;
          float4 v = *(const float4*)(Bfb + (size_t)(ee >> 5) * ldb + ks + (ee & 31));
          uint2 hi, lo;
          split4(v, hi, lo);
          *(uint2*)&BshS[ee] = hi;
          if constexpr (TERMS == 3) *(uint2*)&BslS[ee] = lo;
        }
      } else {
#pragma unroll
        for (int j = 0; j < B_INST; ++j) {
          int ee = (j * 256 + tid) * 8;
          size_t gs = (size_t)(ee >> 5) * ldb + ks + (ee & 31);
          gload_lds16(Bb + gs, (char*)BshS + (size_t)ee * 2);
          if constexpr (TERMS == 3)
            gload_lds16(Bb + planeB + gs, (char*)BslS + (size_t)ee * 2);
        }
      }
    }
    __syncthreads();

#pragma unroll
    for (int s = 0; s < NSUB; ++s) {
      const u16* AshS = Ash + s * BM * BK;
      const u16* AslS = Asl + (TERMS >= 2 ? s * BM * BK : 0);
      const u16* BshS = Bsh + s * BN * BK;
      const u16* BslS = Bsl + (TERMS == 3 ? s * BN * BK : 0);
      short8 ah[FM], al_[FM], bh[FN], bl[FN];
#pragma unroll
      for (int mi = 0; mi < FM; ++mi) {
        int off = (wm0 + mi * 16 + fr) * BK + kb;
        ah[mi] = *(const short8*)&AshS[off];
        if constexpr (TERMS >= 2) al_[mi] = *(const short8*)&AslS[off];
      }
#pragma unroll
      for (int ni = 0; ni < FN; ++ni) {
        int off = (wn0 + ni * 16 + fr) * BK + kb;
        bh[ni] = *(const short8*)&BshS[off];
        if constexpr (TERMS == 3) bl[ni] = *(const short8*)&BslS[off];
      }
#pragma unroll
      for (int mi = 0; mi < FM; ++mi)
#pragma unroll
        for (int ni = 0; ni < FN; ++ni) {
          acc[mi][ni] = __builtin_amdgcn_mfma_f32_16x16x32_bf16(ah[mi], bh[ni], acc[mi][ni], 0, 0, 0);
          if constexpr (TERMS == 3)
            acc[mi][ni] = __builtin_amdgcn_mfma_f32_16x16x32_bf16(ah[mi], bl[ni], acc[mi][ni], 0, 0, 0);
          if constexpr (TERMS >= 2)
            acc[mi][ni] = __builtin_amdgcn_mfma_f32_16x16x32_bf16(al_[mi], bh[ni], acc[mi][ni], 0, 0, 0);
        }
    }
  }
  __syncthreads();

  const size_t offC = (size_t)zb * offC_hi + (size_t)zh * offC_lo;
  const int row0 = by * BM + wm0 + (lane >> 4) * 4;
  const int col0 = bx * BN + wn0 + fr;
  const float* biasp = bias ? bias + (size_t)e * offBias : nullptr;
  const bool addBias = biasp && (SPLITK == 1 || sk == 0);

#pragma unroll
  for (int mi = 0; mi < FM; ++mi) {
#pragma unroll
    for (int ni = 0; ni < FN; ++ni) {
      const int col = col0 + ni * 16;
      const float bv = addBias ? biasp[col] : 0.f;
#pragma unroll
      for (int r = 0; r < 4; ++r) {
        const int row = row0 + mi * 16 + r;
        float v = acc[mi][ni][r] * alpha + bv;
        if constexpr (GELU) v = 0.5f * v * (1.f + erff(v * 0.70710678118f));
        if constexpr (OUTMODE == 4) {
          int sl = row - gaoff[e];
          if (sl < cnte) {
            int lv = glist[e * 2048 + sl];
            int tok = lv >> 1, rank = lv & 1;
            float* p = (float*)Cv + (size_t)rank * planeC + (size_t)tok * ldc + col;
            float out = wf[tok * 2 + rank] * v;
            if constexpr (SPLITK > 1) atomAddF(p, out); else *p = out;
          }
        } else {
          const size_t idx = offC + (size_t)row * ldc + col;
          if constexpr (OUTMODE == 1) {
            u16 hh = f2bf(v);
            u16 ll = f2bf(v - bf2f(hh));
            ((u16*)Cv)[idx] = hh;
            ((u16*)Cv)[idx + planeC] = ll;
          } else if constexpr (OUTMODE == 3) {
            if constexpr (SPLITK > 1) atomAddF((float*)Cv + idx, v);
            else ((float*)Cv)[idx] += v;
          } else {
            ((float*)Cv)[idx] = v;
          }
        }
      }
    }
  }
}

// ---------------------------------------------------------------------------
// Fused attention: ctx = softmax(q k^T / 8) @ v, one block per (bh, 128-q-tile)
// QK+softmax phase: verified round-9 structure, unchanged.
// PV phase: 2 K-steps per barrier pair (separate 8KB sub-buffers, identical
// per-ks arithmetic) — halves the 32 serial barriers (1 block/CU, nothing
// else hides them).
// grid = (1, S/128, B*H), 512 threads, dynamic LDS 84 KiB.
// ---------------------------------------------------------------------------
__global__ __launch_bounds__(512)
void attn_fused(const u16* __restrict__ qkv, long planeQ,
                const u16* __restrict__ vT, long planeV,
                u16* __restrict__ ctxs, long planeC)
{
  constexpr int BK = 32, S = 512;
  extern __shared__ __align__(16) char smem[];
  u16* Ash = (u16*)smem;
  u16* Asl = Ash + 128 * 32;
  u16* Bsh = Asl + 128 * 32;
  u16* Bsl = Bsh + 512 * 32;
  float* redM = (float*)(Bsl + 512 * 32);
  float* redS = redM + 512;
  // PV aliases (QK staging dead by then): 2 sub-buffers per tensor/plane
  u16* Ph0 = (u16*)smem;            // 128*32 each
  u16* Ph1 = Ph0 + 128 * 32;
  u16* Pl0 = Ph1 + 128 * 32;
  u16* Pl1 = Pl0 + 128 * 32;
  u16* Vh0 = Pl1 + 128 * 32;        // 64*32 each
  u16* Vh1 = Vh0 + 64 * 32;
  u16* Vl0 = Vh1 + 64 * 32;
  u16* Vl1 = Vl0 + 64 * 32;

  const int tid = threadIdx.x, lane = tid & 63, wid = tid >> 6;
  const int bh = blockIdx.z, zb = bh >> 4, zh = bh & 15;
  const int qt = blockIdx.y;
  const u16* Ab = qkv + (size_t)zb * (512 * 3072) + (size_t)zh * 64
                      + (size_t)(qt * 128) * 3072;
  const u16* Bb = qkv + (size_t)zb * (512 * 3072) + (size_t)zh * 64 + 1024;
  const u16* vt = vT + (size_t)bh * (64 * 512);

  const int wr = wid >> 2, wc = wid & 3;
  const int fr = lane & 15, kb = (lane >> 4) * 8, g = lane >> 4;

  f32x4 acc[4][8] = {};

  for (int k0 = 0; k0 < 64; k0 += BK) {
    __syncthreads();
    {
      int ee = tid * 8;
      size_t gs = (size_t)(ee >> 5) * 3072 + k0 + (ee & 31);
      gload_lds16(Ab + gs,          (char*)Ash + (size_t)ee * 2);
      gload_lds16(Ab + planeQ + gs, (char*)Asl + (size_t)ee * 2);
    }
#pragma unroll
    for (int j = 0; j < 4; ++j) {
      int ee = (j * 512 + tid) * 8;
      size_t gs = (size_t)(ee >> 5) * 3072 + k0 + (ee & 31);
      gload_lds16(Bb + gs,          (char*)Bsh + (size_t)ee * 2);
      gload_lds16(Bb + planeQ + gs, (char*)Bsl + (size_t)ee * 2);
    }
    __syncthreads();

    short8 ah[4], al_[4];
#pragma unroll
    for (int mi = 0; mi < 4; ++mi) {
      int off = (wr * 64 + mi * 16 + fr) * BK + kb;
      ah[mi]  = *(const short8*)&Ash[off];
      al_[mi] = *(const short8*)&Asl[off];
    }
#pragma unroll
    for (int ni = 0; ni < 8; ++ni) {
      int off = (wc * 128 + ni * 16 + fr) * BK + kb;
      short8 bhv = *(const short8*)&Bsh[off];
      short8 blv = *(const short8*)&Bsl[off];
#pragma unroll
      for (int mi = 0; mi < 4; ++mi) {
        acc[mi][ni] = __builtin_amdgcn_mfma_f32_16x16x32_bf16(ah[mi],  bhv, acc[mi][ni], 0, 0, 0);
        acc[mi][ni] = __builtin_amdgcn_mfma_f32_16x16x32_bf16(ah[mi],  blv, acc[mi][ni], 0, 0, 0);
        acc[mi][ni] = __builtin_amdgcn_mfma_f32_16x16x32_bf16(al_[mi], bhv, acc[mi][ni], 0, 0, 0);
      }
    }
  }

#pragma unroll
  for (int mi = 0; mi < 4; ++mi)
#pragma unroll
    for (int ni = 0; ni < 8; ++ni)
#pragma unroll
      for (int r = 0; r < 4; ++r) acc[mi][ni][r] *= 0.125f;

  float m[4][4];
#pragma unroll
  for (int mi = 0; mi < 4; ++mi)
#pragma unroll
    for (int r = 0; r < 4; ++r) {
      float v = acc[mi][0][r];
#pragma unroll
      for (int ni = 1; ni < 8; ++ni) v = fmaxf(v, acc[mi][ni][r]);
      v = fmaxf(v, __shfl_xor(v, 1));
      v = fmaxf(v, __shfl_xor(v, 2));
      v = fmaxf(v, __shfl_xor(v, 4));
      v = fmaxf(v, __shfl_xor(v, 8));
      m[mi][r] = v;
    }
  if (fr == 0) {
#pragma unroll
    for (int mi = 0; mi < 4; ++mi)
#pragma unroll
      for (int r = 0; r < 4; ++r)
        redM[wr * 256 + (g * 4 + mi * 16 + r) * 4 + wc] = m[mi][r];
  }
  __syncthreads();
#pragma unroll
  for (int mi = 0; mi < 4; ++mi)
#pragma unroll
    for (int r = 0; r < 4; ++r) {
      const float* p = &redM[wr * 256 + (g * 4 + mi * 16 + r) * 4];
      m[mi][r] = fmaxf(fmaxf(p[0], p[1]), fmaxf(p[2], p[3]));
    }

  float ssum[4][4];
#pragma unroll
  for (int mi = 0; mi < 4; ++mi)
#pragma unroll
    for (int r = 0; r < 4; ++r) {
      float ss = 0.f;
#pragma unroll
      for (int ni = 0; ni < 8; ++ni) {
        float p = __expf(acc[mi][ni][r] - m[mi][r]);
        acc[mi][ni][r] = p;
        ss += p;
      }
      ss += __shfl_xor(ss, 1);
      ss += __shfl_xor(ss, 2);
      ss += __shfl_xor(ss, 4);
      ss += __shfl_xor(ss, 8);
      ssum[mi][r] = ss;
    }
  if (fr == 0) {
#pragma unroll
    for (int mi = 0; mi < 4; ++mi)
#pragma unroll
      for (int r = 0; r < 4; ++r)
        redS[wr * 256 + (g * 4 + mi * 16 + r) * 4 + wc] = ssum[mi][r];
  }
  __syncthreads();

#pragma unroll
  for (int mi = 0; mi < 4; ++mi)
#pragma unroll
    for (int r = 0; r < 4; ++r) {
      const float* p = &redS[wr * 256 + (g * 4 + mi * 16 + r) * 4];
      const float inv = 1.f / (p[0] + p[1] + p[2] + p[3]);
#pragma unroll
      for (int ni = 0; ni < 8; ++ni) acc[mi][ni][r] *= inv;
    }

  // ---- PV phase: 2 ks per barrier pair ----
  f32x4 c[4] = {};
#pragma unroll
  for (int kp = 0; kp < 8; ++kp) {
    __syncthreads();   // previous pair's P/V reads done
#pragma unroll
    for (int s = 0; s < 2; ++s) {
      const int ks = kp * 2 + s;
      u16* PhS = s ? Ph1 : Ph0;
      u16* PlS = s ? Pl1 : Pl0;
      if (wc == (ks >> 2)) {
        const int ni0 = (ks & 3) * 2;
#pragma unroll
        for (int mi = 0; mi < 4; ++mi)
#pragma unroll
          for (int dni = 0; dni < 2; ++dni)
#pragma unroll
            for (int r = 0; r < 4; ++r) {
              float v = acc[mi][ni0 + dni][r];
              u16 h = f2bf(v);
              u16 lo = f2bf(v - bf2f(h));
              int row = wr * 64 + mi * 16 + g * 4 + r;
              int koff = dni * 16 + fr;
              PhS[row * 32 + koff] = h;
              PlS[row * 32 + koff] = lo;
            }
      }
    }
    {
      int ee = (tid & 255) * 8;
      size_t gs0 = (size_t)(ee >> 5) * 512 + kp * 64 + (ee & 31);
      if (tid < 256) {
        gload_lds16(vt + gs0,      (char*)Vh0 + (size_t)ee * 2);
        gload_lds16(vt + gs0 + 32, (char*)Vh1 + (size_t)ee * 2);
      } else {
        gload_lds16(vt + planeV + gs0,      (char*)Vl0 + (size_t)ee * 2);
        gload_lds16(vt + planeV + gs0 + 32, (char*)Vl1 + (size_t)ee * 2);
      }
    }
    __syncthreads();

#pragma unroll
    for (int s = 0; s < 2; ++s) {
      const u16* PhS = s ? Ph1 : Ph0;
      const u16* PlS = s ? Pl1 : Pl0;
      const u16* VhS = s ? Vh1 : Vh0;
      const u16* VlS = s ? Vl1 : Vl0;
      short8 pah = *(const short8*)&PhS[(wid * 16 + fr) * 32 + kb];
      short8 pal = *(const short8*)&PlS[(wid * 16 + fr) * 32 + kb];
#pragma unroll
      for (int ni = 0; ni < 4; ++ni) {
        short8 vbh = *(const short8*)&VhS[(ni * 16 + fr) * 32 + kb];
        short8 vbl = *(const short8*)&VlS[(ni * 16 + fr) * 32 + kb];
        c[ni] = __builtin_amdgcn_mfma_f32_16x16x32_bf16(pah, vbh, c[ni], 0, 0, 0);
        c[ni] = __builtin_amdgcn_mfma_f32_16x16x32_bf16(pah, vbl, c[ni], 0, 0, 0);
        c[ni] = __builtin_amdgcn_mfma_f32_16x16x32_bf16(pal, vbh, c[ni], 0, 0, 0);
      }
    }
  }

#pragma unroll
  for (int ni = 0; ni < 4; ++ni)
#pragma unroll
    for (int r = 0; r < 4; ++r) {
      int row = qt * 128 + wid * 16 + g * 4 + r;
      int d = ni * 16 + fr;
      size_t idx = ((size_t)zb * 512 + row) * 1024 + zh * 64 + d;
      float v = c[ni][r];
      u16 h = f2bf(v);
      u16 lo = f2bf(v - bf2f(h));
      ctxs[idx] = h;
      ctxs[idx + planeC] = lo;
    }
}

// ---------------------------------------------------------------------------
__global__ __launch_bounds__(256)
void embed_kernel(const int* __restrict__ ids, const float* __restrict__ tok,
                  const float* __restrict__ pos, float* __restrict__ x,
                  u16* __restrict__ xs, long plane)
{
  const int t = blockIdx.x, c = threadIdx.x;
  const int id = ids[t], s = t & 511;
  float4 tv = ((const float4*)(tok + (size_t)id * 1024))[c];
  float4 pv = ((const float4*)(pos + (size_t)s * 1024))[c];
  float o[4] = {tv.x + pv.x, tv.y + pv.y, tv.z + pv.z, tv.w + pv.w};
  ((float4*)(x + (size_t)t * 1024))[c] = *(float4*)o;
  uint2 uh, ul;
  u16 h0 = f2bf(o[0]), h1 = f2bf(o[1]), h2 = f2bf(o[2]), h3 = f2bf(o[3]);
  uh.x = (unsigned)h0 | ((unsigned)h1 << 16);
  uh.y = (unsigned)h2 | ((unsigned)h3 << 16);
  ul.x = (unsigned)f2bf(o[0] - bf2f(h0)) | ((unsigned)f2bf(o[1] - bf2f(h1)) << 16);
  ul.y = (unsigned)f2bf(o[2] - bf2f(h2)) | ((unsigned)f2bf(o[3] - bf2f(h3)) << 16);
  const size_t idx = (size_t)t * 1024 + c * 4;
  *(uint2*)(xs + idx) = uh;
  *(uint2*)(xs + plane + idx) = ul;
}

// ---------------------------------------------------------------------------
__global__ __launch_bounds__(256)
void ln_kernel(float* __restrict__ x, const float* __restrict__ g,
               const float* __restrict__ b, u16* __restrict__ xs, long plane)
{
  const int row = blockIdx.x, t = threadIdx.x;
  float4 xv = ((const float4*)(x + (size_t)row * 1024))[t];
  float s = xv.x + xv.y + xv.z + xv.w;
  float q = xv.x * xv.x + xv.y * xv.y + xv.z * xv.z + xv.w * xv.w;
#pragma unroll
  for (int o = 32; o; o >>= 1) { s += __shfl_xor(s, o); q += __shfl_xor(q, o); }
  __shared__ float ss[4], qq[4];
  const int wid = t >> 6;
  if ((t & 63) == 0) { ss[wid] = s; qq[wid] = q; }
  __syncthreads();
  s = ss[0] + ss[1] + ss[2] + ss[3];
  q = qq[0] + qq[1] + qq[2] + qq[3];
  const float mean = s * (1.f / 1024.f);
  const float var = q * (1.f / 1024.f) - mean * mean;
  const float rstd = 1.f / sqrtf(var + 1e-5f);
  float4 gv = ((const float4*)g)[t];
  float4 bv = ((const float4*)b)[t];
  float o[4];
  o[0] = (xv.x - mean) * rstd * gv.x + bv.x;
  o[1] = (xv.y - mean) * rstd * gv.y + bv.y;
  o[2] = (xv.z - mean) * rstd * gv.z + bv.z;
  o[3] = (xv.w - mean) * rstd * gv.w + bv.w;
  ((float4*)(x + (size_t)row * 1024))[t] = *(float4*)o;
  uint2 uh, ul;
  u16 h0 = f2bf(o[0]), h1 = f2bf(o[1]), h2 = f2bf(o[2]), h3 = f2bf(o[3]);
  uh.x = (unsigned)h0 | ((unsigned)h1 << 16);
  uh.y = (unsigned)h2 | ((unsigned)h3 << 16);
  ul.x = (unsigned)f2bf(o[0] - bf2f(h0)) | ((unsigned)f2bf(o[1] - bf2f(h1)) << 16);
  ul.y = (unsigned)f2bf(o[2] - bf2f(h2)) | ((unsigned)f2bf(o[3] - bf2f(h3)) << 16);
  const size_t idx = (size_t)row * 1024 + t * 4;
  *(uint2*)(xs + idx) = uh;
  *(uint2*)(xs + plane + idx) = ul;
}

// ---------------------------------------------------------------------------
// V transpose on both planes: vT[bh][d][s] = qkv[b*512+s][2048+h*64+d]
// ---------------------------------------------------------------------------
__global__ __launch_bounds__(256)
void vtrans_kernel(const u16* __restrict__ qkv, u16* __restrict__ vT,
                   long planeQ, long planeV)
{
  __shared__ u16 tile[64][68];
  const u16* src = qkv + (size_t)blockIdx.z * planeQ;
  u16* dst = vT + (size_t)blockIdx.z * planeV;
  const int s0 = blockIdx.x << 6;
  const int bh = blockIdx.y, b = bh >> 4, h = bh & 15;
  const int t = threadIdx.x;
#pragma unroll
  for (int j = 0; j < 16; ++j) {
    int idx = j * 256 + t;
    int sl = idx >> 6, d = idx & 63;
    tile[sl][d] = src[(size_t)(b * 512 + s0 + sl) * 3072 + 2048 + h * 64 + d];
  }
  __syncthreads();
#pragma unroll
  for (int j = 0; j < 16; ++j) {
    int idx = j * 256 + t;
    int d = idx >> 6, sl = idx & 63;
    dst[(size_t)bh * (64 * 512) + (size_t)d * 512 + s0 + sl] = tile[sl][d];
  }
}

// ---------------------------------------------------------------------------
__global__ __launch_bounds__(256)
void router_kernel(const float* __restrict__ x, const float* __restrict__ Wr,
                   const float* __restrict__ br, int2* __restrict__ er,
                   float2* __restrict__ wf)
{
  const int lane = threadIdx.x & 63, wid = threadIdx.x >> 6;
  const int t = blockIdx.x * 4 + wid;
  const float* xr = x + (size_t)t * 1024;
  float xv[16];
#pragma unroll
  for (int j = 0; j < 16; ++j) xv[j] = xr[j * 64 + lane];
  float p[8];
#pragma unroll
  for (int e = 0; e < 8; ++e) {
    const float* wr = Wr + (size_t)e * 1024;
    float s = 0.f;
#pragma unroll
    for (int j = 0; j < 16; ++j) s += xv[j] * wr[j * 64 + lane];
#pragma unroll
    for (int o = 32; o; o >>= 1) s += __shfl_xor(s, o);
    p[e] = s + br[e];
  }
  float m = p[0];
#pragma unroll
  for (int e = 1; e < 8; ++e) m = fmaxf(m, p[e]);
#pragma unroll
  for (int e = 0; e < 8; ++e) p[e] = __expf(p[e] - m);
  int i1 = -1; float v1 = -1.f;
#pragma unroll
  for (int e = 0; e < 8; ++e) if (p[e] > v1) { v1 = p[e]; i1 = e; }
  int i2 = -1; float v2 = -1.f;
#pragma unroll
  for (int e = 0; e < 8; ++e) if (e != i1 && p[e] > v2) { v2 = p[e]; i2 = e; }
  const float inv = 1.f / (v1 + v2);
  if (lane == 0) {
    er[t] = make_int2(i1, i2);
    wf[t] = make_float2(v1 * inv, v2 * inv);
  }
}

// ---------------------------------------------------------------------------
__global__ __launch_bounds__(256)
void build_lists(const int2* __restrict__ er, int* __restrict__ cnt,
                 int* __restrict__ list)
{
  const int t = blockIdx.x * 256 + threadIdx.x;
  int2 e = er[t];
  int s0 = atomicAdd(&cnt[e.x], 1); list[e.x * 2048 + s0] = t * 2;
  int s1 = atomicAdd(&cnt[e.y], 1); list[e.y * 2048 + s1] = t * 2 + 1;
}

// ---------------------------------------------------------------------------
__global__ void finalize_lists(const int* __restrict__ cnt, int* __restrict__ aoff,
                               int* __restrict__ block2e, int nb)
{
  if (threadIdx.x != 0 || blockIdx.x != 0) return;
  for (int b = 0; b < nb; ++b) block2e[b] = -1;
  int off = 0;
  for (int e = 0; e < 8; ++e) {
    aoff[e] = off;
    int pe = ((cnt[e] + 127) >> 7) << 7;
    for (int b = off >> 7; b < (off + pe) >> 7; ++b) block2e[b] = e;
    off += pe;
  }
  aoff[8] = off;
}

// ---------------------------------------------------------------------------
__global__ __launch_bounds__(256)
void combine_split(const float* __restrict__ o0, const float* __restrict__ o1,
                   u16* __restrict__ dh, long plane)
{
  const long i = ((long)blockIdx.x * 256 + threadIdx.x) * 8;
  float4 a0 = ((const float4*)o0)[i / 4];
  float4 a1 = ((const float4*)o0)[i / 4 + 1];
  float4 b0 = ((const float4*)o1)[i / 4];
  float4 b1 = ((const float4*)o1)[i / 4 + 1];
  float v[8] = {a0.x + b0.x, a0.y + b0.y, a0.z + b0.z, a0.w + b0.w,
                a1.x + b1.x, a1.y + b1.y, a1.z + b1.z, a1.w + b1.w};
  u16 h[8], l[8];
#pragma unroll
  for (int j = 0; j < 8; ++j) {
    h[j] = f2bf(v[j]);
    l[j] = f2bf(v[j] - bf2f(h[j]));
  }
  uint4 uh, ul;
  uh.x = (unsigned)h[0] | ((unsigned)h[1] << 16); ul.x = (unsigned)l[0] | ((unsigned)l[1] << 16);
  uh.y = (unsigned)h[2] | ((unsigned)h[3] << 16); ul.y = (unsigned)l[2] | ((unsigned)l[3] << 16);
  uh.z = (unsigned)h[4] | ((unsigned)h[5] << 16); ul.z = (unsigned)l[4] | ((unsigned)l[5] << 16);
  uh.w = (unsigned)h[6] | ((unsigned)h[7] << 16); ul.w = (unsigned)l[6] | ((unsigned)l[7] << 16);
  ((uint4*)dh)[i / 8] = uh;
  ((uint4*)(dh + plane))[i / 8] = ul;
}

// ---------------------------------------------------------------------------
__global__ __launch_bounds__(256)
void trunc_bf16(const float* __restrict__ s, u16* __restrict__ d)
{
  const long i = ((long)blockIdx.x * 256 + threadIdx.x) * 8;
  float4 a = ((const float4*)s)[i / 4];
  float4 b = ((const float4*)s)[i / 4 + 1];
  uint4 u;
  u.x = (unsigned)f2bf(a.x) | ((unsigned)f2bf(a.y) << 16);
  u.y = (unsigned)f2bf(a.z) | ((unsigned)f2bf(a.w) << 16);
  u.z = (unsigned)f2bf(b.x) | ((unsigned)f2bf(b.y) << 16);
  u.w = (unsigned)f2bf(b.z) | ((unsigned)f2bf(b.w) << 16);
  ((uint4*)d)[i / 8] = u;
}

// ---------------------------------------------------------------------------

extern "C" void kernel_launch(void* const* d_in, const int* in_sizes, int n_in,
                              void* d_out, int out_size, void* d_ws, size_t ws_size,
                              hipStream_t stream)
{
  (void)in_sizes; (void)n_in; (void)out_size;
  const int*   ids  = (const int*)d_in[0];
  const float* tok  = (const float*)d_in[2];
  const float* pos  = (const float*)d_in[3];
  const float* Wqkv = (const float*)d_in[4];
  const float* bqkv = (const float*)d_in[5];
  const float* Wo   = (const float*)d_in[6];
  const float* bo   = (const float*)d_in[7];
  const float* ln1g = (const float*)d_in[8];
  const float* ln1b = (const float*)d_in[9];
  const float* ln2g = (const float*)d_in[10];
  const float* ln2b = (const float*)d_in[11];
  const float* W1   = (const float*)d_in[12];
  const float* b1   = (const float*)d_in[13];
  const float* W2   = (const float*)d_in[14];
  const float* b2   = (const float*)d_in[15];
  const float* Wr   = (const float*)d_in[16];
  const float* br   = (const float*)d_in[17];
  const float* We1  = (const float*)d_in[18];
  const float* be1  = (const float*)d_in[19];
  const float* We2  = (const float*)d_in[20];
  const float* be2  = (const float*)d_in[21];
  const float* Wout = (const float*)d_in[22];
  const float* bout = (const float*)d_in[23];

  constexpr int T = 2048, D = 1024, S = 512, Bb = 4, H = 16, dh = 64, F = 4096,
                L = 12, E = 8, V = 32000;
  constexpr int NB = (2 * T + E * 127) / 128 + 1;   // padded slot blocks (40)

  constexpr long PX  = (long)T * D;
  constexpr long PQ  = (long)T * 3 * D;
  constexpr long PFE = (long)(NB * 128) * F;        // padded expert hidden
  constexpr long PV  = (long)Bb * H * dh * S;

  char* w = (char*)d_ws;
  size_t o = 0;
  auto alloc = [&](size_t bytes) -> void* {
    void* p = w + o; o = (o + bytes + 255) & ~(size_t)255; return p;
  };
  float* x    = (float*)alloc((size_t)T * D * 4);
  u16* xs   = (u16*)alloc((size_t)2 * PX * 2);
  u16* moes = (u16*)alloc((size_t)2 * PX * 2);
  u16* qkvs = (u16*)alloc((size_t)2 * PQ * 2);
  u16* ctxs = (u16*)alloc((size_t)2 * PX * 2);
  u16* ffs  = (u16*)alloc((size_t)2 * PFE * 2);
  u16* vTs  = (u16*)alloc((size_t)2 * PV * 2);
  u16* woutb = (u16*)alloc((size_t)V * D * 2);
  float* outr = (float*)alloc((size_t)2 * PX * 4);
  int2*   er  = (int2*)alloc((size_t)T * 8);
  float2* wf  = (float2*)alloc((size_t)T * 8);
  int*    cnt = (int*)alloc((size_t)E * 4);
  int*    list= (int*)alloc((size_t)E * T * 4);
  int*    aoff= (int*)alloc((size_t)(E + 1) * 4);
  int*    b2e = (int*)alloc((size_t)NB * 4);
  if (o > ws_size) return;  // output stays poisoned -> visible failure

  embed_kernel<<<T, 256, 0, stream>>>(ids, tok, pos, x, xs, PX);
  trunc_bf16<<<(V * D) / 2048, 256, 0, stream>>>(Wout, woutb);

  constexpr size_t ATTN_LDS = (4096 + 4096 + 16384 + 16384) * 2 + 2 * 512 * 4;

  for (int l = 0; l < L; ++l) {
    // qkv = xs @ Wqkv^T + bqkv -> split qkvs
    gemm_bt<128,128,2,2,1,false,0,true,1,3>
        <<<dim3(3 * D / 128, T / 128, 1), 256, 0, stream>>>(
        xs, D, PX, 0, 0, Wqkv + (size_t)l * 3 * D * D, D, 0, 0, 0,
        qkvs, 3 * D, PQ, 0, 0, D, 1.f, bqkv + (size_t)l * 3 * D, 0,
        nullptr, nullptr, nullptr, nullptr, nullptr);
    vtrans_kernel<<<dim3(S / 64, Bb * H, 2), 256, 0, stream>>>(qkvs, vTs, PQ, PV);
    // ctx = softmax(q k^T / 8) @ v  (fused; PV 2-ks pairing)
    attn_fused<<<dim3(1, S / 128, Bb * H), 512, ATTN_LDS, stream>>>(
        qkvs, PQ, vTs, PV, ctxs, PX);
    // x += ctx @ Wo^T + bo   (split-K=2, atomic f32)
    gemm_bt<128,128,2,2,3,false,0,true,2,3>
        <<<dim3(D / 128, T / 128, 2), 256, 0, stream>>>(
        ctxs, D, PX, 0, 0, Wo + (size_t)l * D * D, D, 0, 0, 0,
        x, D, 0, 0, 0, D, 1.f, bo + (size_t)l * D, 0,
        nullptr, nullptr, nullptr, nullptr, nullptr);
    ln_kernel<<<T, 256, 0, stream>>>(x, ln1g + (size_t)l * D, ln1b + (size_t)l * D, xs, PX);
    // ff = gelu(xs @ W1^T + b1) -> split ffs
    gemm_bt<128,128,2,2,1,true,0,true,1,3>
        <<<dim3(F / 128, T / 128, 1), 256, 0, stream>>>(
        xs, D, PX, 0, 0, W1 + (size_t)l * F * D, D, 0, 0, 0,
        ffs, F, (long)T * F, 0, 0, D, 1.f, b1 + (size_t)l * F, 0,
        nullptr, nullptr, nullptr, nullptr, nullptr);
    // x += ffs @ W2^T + b2   (split-K=4, atomic f32)
    gemm_bt<128,128,2,2,3,false,0,true,4,3>
        <<<dim3(D / 128, T / 128, 4), 256, 0, stream>>>(
        ffs, F, (long)T * F, 0, 0, W2 + (size_t)l * D * F, F, 0, 0, 0,
        x, D, 0, 0, 0, F, 1.f, b2 + (size_t)l * D, 0,
        nullptr, nullptr, nullptr, nullptr, nullptr);
    ln_kernel<<<T, 256, 0, stream>>>(x, ln2g + (size_t)l * D, ln2b + (size_t)l * D, xs, PX);
  }

  // ---- sparse top-2 MoE (batched experts via 128-padded slot blocks) ----
  router_kernel<<<T / 4, 256, 0, stream>>>(x, Wr, br, er, wf);
  hipMemsetAsync(cnt, 0, E * 4, stream);
  build_lists<<<T / 256, 256, 0, stream>>>(er, cnt, list);
  finalize_lists<<<1, 64, 0, stream>>>(cnt, aoff, b2e, NB);
  hipMemsetAsync(outr, 0, (size_t)2 * PX * 4, stream);

  gemm_bt<128,128,2,2,1,true,1,true,1,2>
      <<<dim3(F / 128, NB, 1), 256, 0, stream>>>(
      xs, D, PX, 0, 0, We1, D, 0, (long)F * D, 0,
      ffs, F, PFE, 0, 0, D, 1.f, be1, F,
      nullptr, list, cnt, b2e, aoff);
  gemm_bt<128,128,2,2,4,false,2,true,2,2>
      <<<dim3(D / 128, NB, 2), 256, 0, stream>>>(
      ffs, F, PFE, 0, 0, We2, F, 0, (long)D * F, 0,
      outr, D, PX, 0, 0, F, 1.f, be2, D,
      (const float*)wf, list, cnt, b2e, aoff);

  combine_split<<<(PX / 2048), 256, 0, stream>>>(outr, outr + PX, moes, PX);

  // logits = moes(hi) @ Wout(bf16)^T + bout -> f32 d_out  (1-term, NSUB=2)
  gemm_bt<128,128,2,2,0,false,0,false,1,1,2>
      <<<dim3(V / 128, T / 128, 1), 256, 0, stream>>>(
      moes, D, PX, 0, 0, woutb, D, 0, 0, 0,
      (float*)d_out, V, 0, 0, 0,
      D, 1.f, bout, 0, nullptr, nullptr, nullptr, nullptr, nullptr);
}